// Round 8
// baseline (1460.888 us; speedup 1.0000x reference)
//
#include <hip/hip_runtime.h>
#include <math.h>

#define NN 100000
#define NE 1000000
#define NG 64
#define NL 4
#define NT_E (NE / 32)
#define NT_N (NN / 32)

typedef __attribute__((ext_vector_type(8))) _Float16 f16x8;
typedef __attribute__((ext_vector_type(4))) float f32x4;

#define MFMA16(a, b, c) __builtin_amdgcn_mfma_f32_16x16x32_f16(a, b, c, 0, 0, 0)
#define LOG2E 1.44269504088896340f
__device__ __forceinline__ float fsig_(float x) {
    return __builtin_amdgcn_rcpf(1.0f + __builtin_amdgcn_exp2f(-LOG2E * x));
}
__device__ __forceinline__ float fsilu_(float x) { return x * fsig_(x); }

__global__ void k_init_h(const float* __restrict__ x, const float* __restrict__ in_w,
                         const float* __restrict__ in_b, float* __restrict__ h32,
                         _Float16* __restrict__ h16) {
    int idx = blockIdx.x * blockDim.x + threadIdx.x;
    if (idx >= NN * 64) return;
    int n = idx >> 6, j = idx & 63;
    float v = fmaf(x[n], in_w[j], in_b[j]);
    h32[idx] = v;
    h16[idx] = (_Float16)v;
}

// transpose + fp16 + zero-pad all weight families x 4 layers
#define SEG0 21504  // 128*168 cw1T
#define SEG1 21504  // ew1T
#define SEG2 8704   // 64*136  ew2T
#define SEG3 17408  // 128*136 nw1T
#define SEG4 8704   // nw2T
#define SEG5 2176   // 16*136  cw2T (O=3 padded to 16)
#define SEGTOT (SEG0 + SEG1 + SEG2 + SEG3 + SEG4 + SEG5)
__global__ void k_prep_all(const float* __restrict__ cw1, const float* __restrict__ ew1,
                           const float* __restrict__ ew2, const float* __restrict__ nw1,
                           const float* __restrict__ nw2, const float* __restrict__ cw2,
                           _Float16* __restrict__ cw1T, _Float16* __restrict__ ew1T,
                           _Float16* __restrict__ ew2T, _Float16* __restrict__ nw1T,
                           _Float16* __restrict__ nw2T, _Float16* __restrict__ cw2T) {
    int i = blockIdx.x * blockDim.x + threadIdx.x;
    if (i >= NL * SEGTOT) return;
    int l = i / SEGTOT, r = i - l * SEGTOT;
    const float* src; _Float16* dst; int K, O, SD, j;
    if (r < SEG0) { src = cw1 + (size_t)l * 131 * 128; dst = cw1T + (size_t)l * SEG0; K = 131; O = 128; SD = 168; j = r; }
    else if ((r -= SEG0) < SEG1) { src = ew1 + (size_t)l * 131 * 128; dst = ew1T + (size_t)l * SEG1; K = 131; O = 128; SD = 168; j = r; }
    else if ((r -= SEG1) < SEG2) { src = ew2 + (size_t)l * 128 * 64; dst = ew2T + (size_t)l * SEG2; K = 128; O = 64; SD = 136; j = r; }
    else if ((r -= SEG2) < SEG3) { src = nw1 + (size_t)l * 128 * 128; dst = nw1T + (size_t)l * SEG3; K = 128; O = 128; SD = 136; j = r; }
    else if ((r -= SEG3) < SEG4) { src = nw2 + (size_t)l * 128 * 64; dst = nw2T + (size_t)l * SEG4; K = 128; O = 64; SD = 136; j = r; }
    else {
        r -= SEG4;
        const float* s2 = cw2 + (size_t)l * 128 * 3;
        int o = r / 136, k = r - o * 136;
        cw2T[(size_t)l * SEG5 + r] = (o < 3 && k < 128) ? (_Float16)s2[(size_t)k * 3 + o] : (_Float16)0.0f;
        return;
    }
    int o = j / SD, k = j - o * SD;
    dst[j] = (k < K) ? (_Float16)src[(size_t)k * O + o] : (_Float16)0.0f;
}

// ---- CSR build ----
__global__ void k_hist(const int* __restrict__ row, int* __restrict__ deg) {
    int e = blockIdx.x * blockDim.x + threadIdx.x;
    if (e < NE) atomicAdd(&deg[row[e]], 1);
}
#define SCB 256
#define SCT 256
#define SCCH ((NN + SCB - 1) / SCB)
__global__ void k_scan_part(const int* __restrict__ deg, int* __restrict__ bsum) {
    __shared__ int red[SCT];
    int b = blockIdx.x;
    int s = b * SCCH, e = min(NN, s + SCCH);
    int sum = 0;
    for (int i = s + threadIdx.x; i < e; i += SCT) sum += deg[i];
    red[threadIdx.x] = sum;
    __syncthreads();
    for (int off = SCT / 2; off > 0; off >>= 1) {
        if (threadIdx.x < off) red[threadIdx.x] += red[threadIdx.x + off];
        __syncthreads();
    }
    if (threadIdx.x == 0) bsum[b] = red[0];
}
__global__ void k_scan_mid(int* __restrict__ bsum) {
    __shared__ int ss[SCB];
    int t = threadIdx.x;
    ss[t] = bsum[t];
    __syncthreads();
    if (t == 0) {
        int run = 0;
        for (int i = 0; i < SCB; ++i) { int v = ss[i]; ss[i] = run; run += v; }
    }
    __syncthreads();
    bsum[t] = ss[t];
}
__global__ void k_scan_fin(const int* __restrict__ deg, const int* __restrict__ bsum,
                           int* __restrict__ rowptr) {
    __shared__ int tsum[SCT];
    int b = blockIdx.x;
    int s = b * SCCH, e = min(NN, s + SCCH);
    const int per = (SCCH + SCT - 1) / SCT;
    int ts = s + threadIdx.x * per;
    int te = min(e, ts + per);
    int sum = 0;
    for (int i = ts; i < te; ++i) sum += deg[i];
    tsum[threadIdx.x] = sum;
    __syncthreads();
    if (threadIdx.x == 0) {
        int run = bsum[b];
        for (int i = 0; i < SCT; ++i) { int v = tsum[i]; tsum[i] = run; run += v; }
    }
    __syncthreads();
    int run = tsum[threadIdx.x];
    for (int i = ts; i < te; ++i) { rowptr[i] = run; run += deg[i]; }
    if (b == 0 && threadIdx.x == 0) rowptr[NN] = NE;
}
__global__ void k_scatter2(const int* __restrict__ row, const int* __restrict__ col,
                           int* __restrict__ pos, int* __restrict__ rowP,
                           int* __restrict__ colP) {
    int e = blockIdx.x * blockDim.x + threadIdx.x;
    if (e < NE) {
        int r = row[e];
        int p = atomicAdd(&pos[r], 1);
        rowP[p] = r;
        colP[p] = col[e];
    }
}

// ---- coord: block-coop GEMM1 + ks-split GEMM2; CSR=1 -> write deltas[slot]
template <int CSR>
__global__ __launch_bounds__(256)
void k_coord3(const _Float16* __restrict__ h16,
              const float* __restrict__ ccur, float* __restrict__ cnext,
              const int* __restrict__ rowP, const int* __restrict__ colP,
              float4* __restrict__ deltas,
              const _Float16* __restrict__ w1T, const float* __restrict__ b1,
              const _Float16* __restrict__ w2T, const float* __restrict__ b2,
              const float* __restrict__ eww, const float* __restrict__ ewb,
              const float* __restrict__ cns) {
    __shared__ __attribute__((aligned(16))) _Float16 cin[32][168];
    __shared__ __attribute__((aligned(16))) _Float16 h1[32][136];
    __shared__ __attribute__((aligned(16))) float pbuf[4][32][17];
    __shared__ float gate[32];
    for (int i = threadIdx.x; i < 32 * 168; i += 256) (&cin[0][0])[i] = (_Float16)0.0f;
    int tid = threadIdx.x;
    int w = tid >> 6, lane = tid & 63, lc = lane & 15, lg = lane >> 4;
    float e0w = eww[0], e1w = eww[1], e2w = eww[2], ebw = ewb[0], sc = cns[0];
    float b20 = b2[0], b21 = b2[1], b22 = b2[2];
    f16x8 bw1[2][5];
#pragma unroll
    for (int ti = 0; ti < 2; ++ti)
#pragma unroll
        for (int ks = 0; ks < 5; ++ks)
            bw1[ti][ks] = *(const f16x8*)&w1T[(size_t)((2 * w + ti) * 16 + lc) * 168 + ks * 32 + lg * 8];
    f16x8 bw2 = *(const f16x8*)&w2T[(size_t)lc * 136 + w * 32 + lg * 8];
    float bias10 = b1[(2 * w) * 16 + lc], bias11 = b1[(2 * w + 1) * 16 + lc];
    __syncthreads();

    for (int tile = blockIdx.x; tile < NT_E; tile += gridDim.x) {
        int e0 = tile * 32;
        {
            int el = tid >> 3, part = tid & 7;
            int r = rowP[e0 + el], c = colP[e0 + el];
            *(f16x8*)&cin[el][part * 8] = *(const f16x8*)&h16[(size_t)r * 64 + part * 8];
            *(f16x8*)&cin[el][64 + part * 8] = *(const f16x8*)&h16[(size_t)c * 64 + part * 8];
        }
        if (tid < 32) {
            int r = rowP[e0 + tid], c = colP[e0 + tid];
            float rx = ccur[r * 3 + 0] - ccur[c * 3 + 0];
            float ry = ccur[r * 3 + 1] - ccur[c * 3 + 1];
            float rz = ccur[r * 3 + 2] - ccur[c * 3 + 2];
            cin[tid][128] = (_Float16)rx; cin[tid][129] = (_Float16)ry; cin[tid][130] = (_Float16)rz;
            gate[tid] = fsig_(fmaf(rx, e0w, fmaf(ry, e1w, fmaf(rz, e2w, ebw))));
        }
        __syncthreads();
        f32x4 acc[2][2];
        acc[0][0] = acc[0][1] = acc[1][0] = acc[1][1] = (f32x4){0.f, 0.f, 0.f, 0.f};
#pragma unroll
        for (int ks = 0; ks < 5; ++ks) {
            f16x8 a0 = *(const f16x8*)&cin[lc][ks * 32 + lg * 8];
            f16x8 a1 = *(const f16x8*)&cin[16 + lc][ks * 32 + lg * 8];
#pragma unroll
            for (int ti = 0; ti < 2; ++ti) {
                acc[0][ti] = MFMA16(a0, bw1[ti][ks], acc[0][ti]);
                acc[1][ti] = MFMA16(a1, bw1[ti][ks], acc[1][ti]);
            }
        }
#pragma unroll
        for (int ti = 0; ti < 2; ++ti) {
            int colc = (2 * w + ti) * 16 + lc;
            float bias = ti ? bias11 : bias10;
#pragma unroll
            for (int rt = 0; rt < 2; ++rt)
#pragma unroll
                for (int j = 0; j < 4; ++j)
                    h1[rt * 16 + lg * 4 + j][colc] = (_Float16)fsilu_(acc[rt][ti][j] + bias);
        }
        __syncthreads();
        f32x4 c2[2];
        c2[0] = c2[1] = (f32x4){0.f, 0.f, 0.f, 0.f};
        {
            f16x8 a0 = *(const f16x8*)&h1[lc][w * 32 + lg * 8];
            f16x8 a1 = *(const f16x8*)&h1[16 + lc][w * 32 + lg * 8];
            c2[0] = MFMA16(a0, bw2, c2[0]);
            c2[1] = MFMA16(a1, bw2, c2[1]);
        }
#pragma unroll
        for (int rt = 0; rt < 2; ++rt)
#pragma unroll
            for (int j = 0; j < 4; ++j)
                pbuf[w][rt * 16 + lg * 4 + j][lc] = c2[rt][j];
        __syncthreads();
        if (tid < 32) {
            float d0 = pbuf[0][tid][0] + pbuf[1][tid][0] + pbuf[2][tid][0] + pbuf[3][tid][0] + b20;
            float d1 = pbuf[0][tid][1] + pbuf[1][tid][1] + pbuf[2][tid][1] + pbuf[3][tid][1] + b21;
            float d2 = pbuf[0][tid][2] + pbuf[1][tid][2] + pbuf[2][tid][2] + pbuf[3][tid][2] + b22;
            float ss = d0 * d0 + d1 * d1 + d2 * d2;
            float nrm = fmaxf(__builtin_amdgcn_sqrtf(ss), 1e-8f);
            float m = sc * __builtin_amdgcn_rcpf(nrm) * gate[tid];
            if (CSR) {
                deltas[e0 + tid] = make_float4(d0 * m, d1 * m, d2 * m, 0.0f);
            } else {
                int r = rowP[e0 + tid];
                atomicAdd(&cnext[(size_t)r * 3 + 0], d0 * m);
                atomicAdd(&cnext[(size_t)r * 3 + 1], d1 * m);
                atomicAdd(&cnext[(size_t)r * 3 + 2], d2 * m);
            }
        }
    }
}

__global__ void k_coord_apply(const float* __restrict__ ccur, float* __restrict__ cnext,
                              const int* __restrict__ rowptr,
                              const float4* __restrict__ deltas) {
    int n = blockIdx.x * blockDim.x + threadIdx.x;
    if (n >= NN) return;
    int s = rowptr[n], e = rowptr[n + 1];
    float d0 = 0.f, d1 = 0.f, d2 = 0.f;
    for (int j = s; j < e; ++j) {
        float4 d = deltas[j];
        d0 += d.x; d1 += d.y; d2 += d.z;
    }
    cnext[(size_t)n * 3 + 0] = ccur[(size_t)n * 3 + 0] + d0;
    cnext[(size_t)n * 3 + 1] = ccur[(size_t)n * 3 + 1] + d1;
    cnext[(size_t)n * 3 + 2] = ccur[(size_t)n * 3 + 2] + d2;
}

// ---- FUSED edge+node: one block per 32-node tile; edges contiguous via CSR.
// Messages accumulated into LDS aggL (f32), node MLP runs in the same block.
// Reads h16cur/h32cur, writes h16nxt/h32nxt (double-buffered: no cross-block race).
__global__ __launch_bounds__(256)
void k_edge_node(const _Float16* __restrict__ h16cur, const float* __restrict__ h32cur,
                 _Float16* __restrict__ h16nxt, float* __restrict__ h32nxt,
                 const float* __restrict__ coords,
                 const int* __restrict__ rowP, const int* __restrict__ colP,
                 const int* __restrict__ rowptr,
                 const _Float16* __restrict__ ew1T, const float* __restrict__ eb1,
                 const _Float16* __restrict__ ew2T, const float* __restrict__ eb2,
                 const _Float16* __restrict__ nw1T, const float* __restrict__ nb1,
                 const _Float16* __restrict__ nw2T, const float* __restrict__ nb2) {
    __shared__ __attribute__((aligned(16))) _Float16 cin[32][168];
    __shared__ __attribute__((aligned(16))) _Float16 h1[32][136];
    __shared__ __attribute__((aligned(16))) _Float16 msg[32][72];
    __shared__ __attribute__((aligned(16))) float aggL[32][64];
    __shared__ int lrL[32];
    int tid = threadIdx.x;
    int w = tid >> 6, lane = tid & 63, lc = lane & 15, lg = lane >> 4;
    int n0 = blockIdx.x * 32;

    // zero cin pad + aggL
    for (int i = tid; i < 32 * 168; i += 256) (&cin[0][0])[i] = (_Float16)0.0f;
    for (int i = tid; i < 32 * 64; i += 256) (&aggL[0][0])[i] = 0.0f;

    // edge-MLP weight fragments in registers
    f16x8 bw1[2][5];
#pragma unroll
    for (int ti = 0; ti < 2; ++ti)
#pragma unroll
        for (int ks = 0; ks < 5; ++ks)
            bw1[ti][ks] = *(const f16x8*)&ew1T[(size_t)((2 * w + ti) * 16 + lc) * 168 + ks * 32 + lg * 8];
    f16x8 bw2[4];
#pragma unroll
    for (int ks = 0; ks < 4; ++ks)
        bw2[ks] = *(const f16x8*)&ew2T[(size_t)(w * 16 + lc) * 136 + ks * 32 + lg * 8];
    float ebias10 = eb1[(2 * w) * 16 + lc], ebias11 = eb1[(2 * w + 1) * 16 + lc];
    float ebias2 = eb2[w * 16 + lc];
    __syncthreads();

    int eBeg = rowptr[n0], eEnd = rowptr[n0 + 32];
    for (int e0 = eBeg; e0 < eEnd; e0 += 32) {
        int nval = min(32, eEnd - e0);
        {   // stage
            int el = tid >> 3, part = tid & 7;
            if (el < nval) {
                int r = rowP[e0 + el], c = colP[e0 + el];
                *(f16x8*)&cin[el][part * 8] = *(const f16x8*)&h16cur[(size_t)r * 64 + part * 8];
                *(f16x8*)&cin[el][64 + part * 8] = *(const f16x8*)&h16cur[(size_t)c * 64 + part * 8];
            }
            if (tid < 32) {
                if (tid < nval) {
                    int r = rowP[e0 + tid], c = colP[e0 + tid];
                    cin[tid][128] = (_Float16)(coords[r * 3 + 0] - coords[c * 3 + 0]);
                    cin[tid][129] = (_Float16)(coords[r * 3 + 1] - coords[c * 3 + 1]);
                    cin[tid][130] = (_Float16)(coords[r * 3 + 2] - coords[c * 3 + 2]);
                    lrL[tid] = rowP[e0 + tid] - n0;
                } else {
                    lrL[tid] = -1;
                }
            }
        }
        __syncthreads();
        f32x4 acc[2][2];
        acc[0][0] = acc[0][1] = acc[1][0] = acc[1][1] = (f32x4){0.f, 0.f, 0.f, 0.f};
#pragma unroll
        for (int ks = 0; ks < 5; ++ks) {
            f16x8 a0 = *(const f16x8*)&cin[lc][ks * 32 + lg * 8];
            f16x8 a1 = *(const f16x8*)&cin[16 + lc][ks * 32 + lg * 8];
#pragma unroll
            for (int ti = 0; ti < 2; ++ti) {
                acc[0][ti] = MFMA16(a0, bw1[ti][ks], acc[0][ti]);
                acc[1][ti] = MFMA16(a1, bw1[ti][ks], acc[1][ti]);
            }
        }
#pragma unroll
        for (int ti = 0; ti < 2; ++ti) {
            int colc = (2 * w + ti) * 16 + lc;
            float bias = ti ? ebias11 : ebias10;
#pragma unroll
            for (int rt = 0; rt < 2; ++rt)
#pragma unroll
                for (int j = 0; j < 4; ++j)
                    h1[rt * 16 + lg * 4 + j][colc] = (_Float16)fsilu_(acc[rt][ti][j] + bias);
        }
        __syncthreads();
        f32x4 c2[2];
        c2[0] = c2[1] = (f32x4){0.f, 0.f, 0.f, 0.f};
#pragma unroll
        for (int ks = 0; ks < 4; ++ks) {
            f16x8 a0 = *(const f16x8*)&h1[lc][ks * 32 + lg * 8];
            f16x8 a1 = *(const f16x8*)&h1[16 + lc][ks * 32 + lg * 8];
            c2[0] = MFMA16(a0, bw2[ks], c2[0]);
            c2[1] = MFMA16(a1, bw2[ks], c2[1]);
        }
#pragma unroll
        for (int rt = 0; rt < 2; ++rt)
#pragma unroll
            for (int j = 0; j < 4; ++j)
                msg[rt * 16 + lg * 4 + j][w * 16 + lc] = (_Float16)fsilu_(c2[rt][j] + ebias2);
        __syncthreads();
        {   // run-compressed accumulate msg -> aggL
            int colj = tid & 63, stripe = tid >> 6;
            int r0 = stripe * 8;
            float a = 0.0f;
            int prev = -1;
            for (int r = r0; r < r0 + 8; ++r) {
                if (r >= nval) break;
                int lr = lrL[r];
                if (lr != prev) {
                    if (prev >= 0) atomicAdd(&aggL[prev][colj], a);
                    a = 0.0f; prev = lr;
                }
                a += (float)msg[r][colj];
            }
            if (prev >= 0) atomicAdd(&aggL[prev][colj], a);
        }
        __syncthreads();
    }

    // ---- node phase ----
    f16x8 nbw1[2][4], nbw2[4];
#pragma unroll
    for (int ti = 0; ti < 2; ++ti)
#pragma unroll
        for (int ks = 0; ks < 4; ++ks)
            nbw1[ti][ks] = *(const f16x8*)&nw1T[(size_t)((2 * w + ti) * 16 + lc) * 136 + ks * 32 + lg * 8];
#pragma unroll
    for (int ks = 0; ks < 4; ++ks)
        nbw2[ks] = *(const f16x8*)&nw2T[(size_t)(w * 16 + lc) * 136 + ks * 32 + lg * 8];
    float nbias10 = nb1[(2 * w) * 16 + lc], nbias11 = nb1[(2 * w + 1) * 16 + lc];
    float nbias2 = nb2[w * 16 + lc];
    {   // stage node input: [h | agg]
        int nl = tid >> 3, part = tid & 7;
        int n = n0 + nl;
        *(f16x8*)&cin[nl][part * 8] = *(const f16x8*)&h16cur[(size_t)n * 64 + part * 8];
        f32x4 xx = *(const f32x4*)&aggL[nl][part * 8];
        f32x4 yy = *(const f32x4*)&aggL[nl][part * 8 + 4];
        f16x8 o;
        o[0] = (_Float16)xx[0]; o[1] = (_Float16)xx[1]; o[2] = (_Float16)xx[2]; o[3] = (_Float16)xx[3];
        o[4] = (_Float16)yy[0]; o[5] = (_Float16)yy[1]; o[6] = (_Float16)yy[2]; o[7] = (_Float16)yy[3];
        *(f16x8*)&cin[nl][64 + part * 8] = o;
    }
    __syncthreads();
    f32x4 acc[2][2];
    acc[0][0] = acc[0][1] = acc[1][0] = acc[1][1] = (f32x4){0.f, 0.f, 0.f, 0.f};
#pragma unroll
    for (int ks = 0; ks < 4; ++ks) {
        f16x8 a0 = *(const f16x8*)&cin[lc][ks * 32 + lg * 8];
        f16x8 a1 = *(const f16x8*)&cin[16 + lc][ks * 32 + lg * 8];
#pragma unroll
        for (int ti = 0; ti < 2; ++ti) {
            acc[0][ti] = MFMA16(a0, nbw1[ti][ks], acc[0][ti]);
            acc[1][ti] = MFMA16(a1, nbw1[ti][ks], acc[1][ti]);
        }
    }
#pragma unroll
    for (int ti = 0; ti < 2; ++ti) {
        int colc = (2 * w + ti) * 16 + lc;
        float bias = ti ? nbias11 : nbias10;
#pragma unroll
        for (int rt = 0; rt < 2; ++rt)
#pragma unroll
            for (int j = 0; j < 4; ++j)
                h1[rt * 16 + lg * 4 + j][colc] = (_Float16)fsilu_(acc[rt][ti][j] + bias);
    }
    __syncthreads();
    f32x4 c2[2];
    c2[0] = c2[1] = (f32x4){0.f, 0.f, 0.f, 0.f};
#pragma unroll
    for (int ks = 0; ks < 4; ++ks) {
        f16x8 a0 = *(const f16x8*)&h1[lc][ks * 32 + lg * 8];
        f16x8 a1 = *(const f16x8*)&h1[16 + lc][ks * 32 + lg * 8];
        c2[0] = MFMA16(a0, nbw2[ks], c2[0]);
        c2[1] = MFMA16(a1, nbw2[ks], c2[1]);
    }
    float (*vbuf)[64] = (float(*)[64])&cin[0][0];  // overlay: cin no longer needed
#pragma unroll
    for (int rt = 0; rt < 2; ++rt)
#pragma unroll
        for (int j = 0; j < 4; ++j) {
            int rl = rt * 16 + lg * 4 + j, colc = w * 16 + lc;
            vbuf[rl][colc] = h32cur[(size_t)(n0 + rl) * 64 + colc] + c2[rt][j] + nbias2;
        }
    __syncthreads();
    {
        int r = w * 8 + (lane >> 3), sub = lane & 7;
        f32x4 v0 = *(const f32x4*)&vbuf[r][sub * 8];
        f32x4 v1 = *(const f32x4*)&vbuf[r][sub * 8 + 4];
        float s = v0[0] + v0[1] + v0[2] + v0[3] + v1[0] + v1[1] + v1[2] + v1[3];
        float sq = v0[0]*v0[0] + v0[1]*v0[1] + v0[2]*v0[2] + v0[3]*v0[3]
                 + v1[0]*v1[0] + v1[1]*v1[1] + v1[2]*v1[2] + v1[3]*v1[3];
        s += __shfl_xor(s, 1); s += __shfl_xor(s, 2); s += __shfl_xor(s, 4);
        sq += __shfl_xor(sq, 1); sq += __shfl_xor(sq, 2); sq += __shfl_xor(sq, 4);
        float mu = s * (1.0f / 64.0f);
        float var = sq * (1.0f / 64.0f) - mu * mu;
        float rs = __builtin_amdgcn_rcpf(__builtin_amdgcn_sqrtf(var + 1e-5f));
        size_t base = (size_t)(n0 + r) * 64 + sub * 8;
        f32x4 o0, o1; f16x8 oh;
#pragma unroll
        for (int i = 0; i < 4; ++i) {
            o0[i] = (v0[i] - mu) * rs;
            o1[i] = (v1[i] - mu) * rs;
            oh[i] = (_Float16)o0[i];
            oh[4 + i] = (_Float16)o1[i];
        }
        *(f32x4*)&h32nxt[base] = o0;
        *(f32x4*)&h32nxt[base + 4] = o1;
        *(f16x8*)&h16nxt[base] = oh;
    }
}

// ---- legacy fallback: edge atomic-agg + separate node (in-place h) ----
__global__ __launch_bounds__(256)
void k_edge_legacy(const _Float16* __restrict__ h16, const float* __restrict__ coords,
                   float* __restrict__ agg,
                   const int* __restrict__ row, const int* __restrict__ col,
                   const _Float16* __restrict__ w1T, const float* __restrict__ b1,
                   const _Float16* __restrict__ w2T, const float* __restrict__ b2) {
    __shared__ __attribute__((aligned(16))) _Float16 cin[32][168];
    __shared__ __attribute__((aligned(16))) _Float16 h1[32][136];
    for (int i = threadIdx.x; i < 32 * 168; i += 256) (&cin[0][0])[i] = (_Float16)0.0f;
    int tid = threadIdx.x;
    int w = tid >> 6, lane = tid & 63, lc = lane & 15, lg = lane >> 4;
    f16x8 bw1[2][5];
#pragma unroll
    for (int ti = 0; ti < 2; ++ti)
#pragma unroll
        for (int ks = 0; ks < 5; ++ks)
            bw1[ti][ks] = *(const f16x8*)&w1T[(size_t)((2 * w + ti) * 16 + lc) * 168 + ks * 32 + lg * 8];
    f16x8 bw2[4];
#pragma unroll
    for (int ks = 0; ks < 4; ++ks)
        bw2[ks] = *(const f16x8*)&w2T[(size_t)(w * 16 + lc) * 136 + ks * 32 + lg * 8];
    float bias10 = b1[(2 * w) * 16 + lc], bias11 = b1[(2 * w + 1) * 16 + lc];
    float bias2 = b2[w * 16 + lc];
    __syncthreads();
    for (int tile = blockIdx.x; tile < NT_E; tile += gridDim.x) {
        int e0 = tile * 32;
        {
            int el = tid >> 3, part = tid & 7;
            int r = row[e0 + el], c = col[e0 + el];
            *(f16x8*)&cin[el][part * 8] = *(const f16x8*)&h16[(size_t)r * 64 + part * 8];
            *(f16x8*)&cin[el][64 + part * 8] = *(const f16x8*)&h16[(size_t)c * 64 + part * 8];
        }
        if (tid < 32) {
            int r = row[e0 + tid], c = col[e0 + tid];
            cin[tid][128] = (_Float16)(coords[r * 3 + 0] - coords[c * 3 + 0]);
            cin[tid][129] = (_Float16)(coords[r * 3 + 1] - coords[c * 3 + 1]);
            cin[tid][130] = (_Float16)(coords[r * 3 + 2] - coords[c * 3 + 2]);
        }
        __syncthreads();
        f32x4 acc[2][2];
        acc[0][0] = acc[0][1] = acc[1][0] = acc[1][1] = (f32x4){0.f, 0.f, 0.f, 0.f};
#pragma unroll
        for (int ks = 0; ks < 5; ++ks) {
            f16x8 a0 = *(const f16x8*)&cin[lc][ks * 32 + lg * 8];
            f16x8 a1 = *(const f16x8*)&cin[16 + lc][ks * 32 + lg * 8];
#pragma unroll
            for (int ti = 0; ti < 2; ++ti) {
                acc[0][ti] = MFMA16(a0, bw1[ti][ks], acc[0][ti]);
                acc[1][ti] = MFMA16(a1, bw1[ti][ks], acc[1][ti]);
            }
        }
#pragma unroll
        for (int ti = 0; ti < 2; ++ti) {
            int colc = (2 * w + ti) * 16 + lc;
            float bias = ti ? bias11 : bias10;
#pragma unroll
            for (int rt = 0; rt < 2; ++rt)
#pragma unroll
                for (int j = 0; j < 4; ++j)
                    h1[rt * 16 + lg * 4 + j][colc] = (_Float16)fsilu_(acc[rt][ti][j] + bias);
        }
        __syncthreads();
        f32x4 c2[2];
        c2[0] = c2[1] = (f32x4){0.f, 0.f, 0.f, 0.f};
#pragma unroll
        for (int ks = 0; ks < 4; ++ks) {
            f16x8 a0 = *(const f16x8*)&h1[lc][ks * 32 + lg * 8];
            f16x8 a1 = *(const f16x8*)&h1[16 + lc][ks * 32 + lg * 8];
            c2[0] = MFMA16(a0, bw2[ks], c2[0]);
            c2[1] = MFMA16(a1, bw2[ks], c2[1]);
        }
#pragma unroll
        for (int rt = 0; rt < 2; ++rt)
#pragma unroll
            for (int j = 0; j < 4; ++j)
                atomicAdd(&agg[(size_t)row[e0 + rt * 16 + lg * 4 + j] * 64 + w * 16 + lc],
                          fsilu_(c2[rt][j] + bias2));
        __syncthreads();
    }
}

__global__ __launch_bounds__(256)
void k_node_legacy(float* __restrict__ h32, _Float16* __restrict__ h16,
                   const float* __restrict__ agg,
                   const _Float16* __restrict__ w1T, const float* __restrict__ b1,
                   const _Float16* __restrict__ w2T, const float* __restrict__ b2) {
    __shared__ __attribute__((aligned(16))) _Float16 cin[32][136];
    __shared__ __attribute__((aligned(16))) _Float16 h1[32][136];
    __shared__ __attribute__((aligned(16))) float vbuf[32][64];
    int tid = threadIdx.x;
    int w = tid >> 6, lane = tid & 63, lc = lane & 15, lg = lane >> 4;
    f16x8 bw1[2][4], bw2[4];
#pragma unroll
    for (int ti = 0; ti < 2; ++ti)
#pragma unroll
        for (int ks = 0; ks < 4; ++ks)
            bw1[ti][ks] = *(const f16x8*)&w1T[(size_t)((2 * w + ti) * 16 + lc) * 136 + ks * 32 + lg * 8];
#pragma unroll
    for (int ks = 0; ks < 4; ++ks)
        bw2[ks] = *(const f16x8*)&w2T[(size_t)(w * 16 + lc) * 136 + ks * 32 + lg * 8];
    float bias10 = b1[(2 * w) * 16 + lc], bias11 = b1[(2 * w + 1) * 16 + lc];
    float bias2 = b2[w * 16 + lc];
    for (int tile = blockIdx.x; tile < NT_N; tile += gridDim.x) {
        int n0 = tile * 32;
        {
            int nl = tid >> 3, part = tid & 7;
            int n = n0 + nl;
            *(f16x8*)&cin[nl][part * 8] = *(const f16x8*)&h16[(size_t)n * 64 + part * 8];
            f32x4 xx = *(const f32x4*)&agg[(size_t)n * 64 + part * 8];
            f32x4 yy = *(const f32x4*)&agg[(size_t)n * 64 + part * 8 + 4];
            f16x8 o;
            o[0] = (_Float16)xx[0]; o[1] = (_Float16)xx[1]; o[2] = (_Float16)xx[2]; o[3] = (_Float16)xx[3];
            o[4] = (_Float16)yy[0]; o[5] = (_Float16)yy[1]; o[6] = (_Float16)yy[2]; o[7] = (_Float16)yy[3];
            *(f16x8*)&cin[nl][64 + part * 8] = o;
        }
        __syncthreads();
        f32x4 acc[2][2];
        acc[0][0] = acc[0][1] = acc[1][0] = acc[1][1] = (f32x4){0.f, 0.f, 0.f, 0.f};
#pragma unroll
        for (int ks = 0; ks < 4; ++ks) {
            f16x8 a0 = *(const f16x8*)&cin[lc][ks * 32 + lg * 8];
            f16x8 a1 = *(const f16x8*)&cin[16 + lc][ks * 32 + lg * 8];
#pragma unroll
            for (int ti = 0; ti < 2; ++ti) {
                acc[0][ti] = MFMA16(a0, bw1[ti][ks], acc[0][ti]);
                acc[1][ti] = MFMA16(a1, bw1[ti][ks], acc[1][ti]);
            }
        }
#pragma unroll
        for (int ti = 0; ti < 2; ++ti) {
            int colc = (2 * w + ti) * 16 + lc;
            float bias = ti ? bias11 : bias10;
#pragma unroll
            for (int rt = 0; rt < 2; ++rt)
#pragma unroll
                for (int j = 0; j < 4; ++j)
                    h1[rt * 16 + lg * 4 + j][colc] = (_Float16)fsilu_(acc[rt][ti][j] + bias);
        }
        __syncthreads();
        f32x4 c2[2];
        c2[0] = c2[1] = (f32x4){0.f, 0.f, 0.f, 0.f};
#pragma unroll
        for (int ks = 0; ks < 4; ++ks) {
            f16x8 a0 = *(const f16x8*)&h1[lc][ks * 32 + lg * 8];
            f16x8 a1 = *(const f16x8*)&h1[16 + lc][ks * 32 + lg * 8];
            c2[0] = MFMA16(a0, bw2[ks], c2[0]);
            c2[1] = MFMA16(a1, bw2[ks], c2[1]);
        }
#pragma unroll
        for (int rt = 0; rt < 2; ++rt)
#pragma unroll
            for (int j = 0; j < 4; ++j) {
                int rl = rt * 16 + lg * 4 + j, colc = w * 16 + lc;
                vbuf[rl][colc] = h32[(size_t)(n0 + rl) * 64 + colc] + c2[rt][j] + bias2;
            }
        __syncthreads();
        {
            int r = w * 8 + (lane >> 3), sub = lane & 7;
            f32x4 v0 = *(const f32x4*)&vbuf[r][sub * 8];
            f32x4 v1 = *(const f32x4*)&vbuf[r][sub * 8 + 4];
            float s = v0[0] + v0[1] + v0[2] + v0[3] + v1[0] + v1[1] + v1[2] + v1[3];
            float sq = v0[0]*v0[0] + v0[1]*v0[1] + v0[2]*v0[2] + v0[3]*v0[3]
                     + v1[0]*v1[0] + v1[1]*v1[1] + v1[2]*v1[2] + v1[3]*v1[3];
            s += __shfl_xor(s, 1); s += __shfl_xor(s, 2); s += __shfl_xor(s, 4);
            sq += __shfl_xor(sq, 1); sq += __shfl_xor(sq, 2); sq += __shfl_xor(sq, 4);
            float mu = s * (1.0f / 64.0f);
            float var = sq * (1.0f / 64.0f) - mu * mu;
            float rs = __builtin_amdgcn_rcpf(__builtin_amdgcn_sqrtf(var + 1e-5f));
            size_t base = (size_t)(n0 + r) * 64 + sub * 8;
            f32x4 o0, o1; f16x8 oh;
#pragma unroll
            for (int i = 0; i < 4; ++i) {
                o0[i] = (v0[i] - mu) * rs;
                o1[i] = (v1[i] - mu) * rs;
                oh[i] = (_Float16)o0[i];
                oh[4 + i] = (_Float16)o1[i];
            }
            *(f32x4*)&h32[base] = o0;
            *(f32x4*)&h32[base + 4] = o1;
            *(f16x8*)&h16[base] = oh;
        }
        __syncthreads();
    }
}

__global__ void k_pool_seg(const float* __restrict__ h, const int* __restrict__ batch,
                           float* __restrict__ pooled, float* __restrict__ cnt) {
    int lane = threadIdx.x & 63;
    int wid = blockIdx.x * (blockDim.x >> 6) + (threadIdx.x >> 6);
    int nwav = gridDim.x * (blockDim.x >> 6);
    int chunk = (NN + nwav - 1) / nwav;
    int s = wid * chunk;
    if (s >= NN) return;
    int e = s + chunk; if (e > NN) e = NN;
    int g = batch[s];
    float acc = 0.0f, c = 0.0f;
    for (int n = s; n < e; ++n) {
        int b = batch[n];
        if (b != g) {
            atomicAdd(&pooled[g * 64 + lane], acc);
            if (lane == 0) atomicAdd(&cnt[g], c);
            acc = 0.0f; c = 0.0f; g = b;
        }
        acc += h[(size_t)n * 64 + lane];
        c += 1.0f;
    }
    atomicAdd(&pooled[g * 64 + lane], acc);
    if (lane == 0) atomicAdd(&cnt[g], c);
}

__global__ void k_final(const float* __restrict__ pooled, const float* __restrict__ cnt,
                        const float* __restrict__ ow, const float* __restrict__ ob,
                        float* __restrict__ out) {
    __shared__ float red[2];
    int g = blockIdx.x, o = threadIdx.x;
    float c = fmaxf(cnt[g], 1.0f);
    float acc = ob[o];
#pragma unroll
    for (int j = 0; j < 64; ++j) {
        float pm = fmaxf(pooled[g * 64 + j] / c, 0.0f);
        acc = fmaf(pm, ow[j * 128 + o], acc);
    }
    float ss = acc * acc;
#pragma unroll
    for (int off = 32; off > 0; off >>= 1) ss += __shfl_xor(ss, off);
    if ((o & 63) == 0) red[o >> 6] = ss;
    __syncthreads();
    float nrm = sqrtf(red[0] + red[1]);
    out[g * 128 + o] = acc / fmaxf(nrm, 1e-12f);
}

extern "C" void kernel_launch(void* const* d_in, const int* in_sizes, int n_in,
                              void* d_out, int out_size, void* d_ws, size_t ws_size,
                              hipStream_t stream) {
    const float* x         = (const float*)d_in[0];
    const float* coords_in = (const float*)d_in[1];
    const float* in_w      = (const float*)d_in[2];
    const float* in_b      = (const float*)d_in[3];
    const float* coord_w1  = (const float*)d_in[4];
    const float* coord_b1  = (const float*)d_in[5];
    const float* coord_w2  = (const float*)d_in[6];
    const float* coord_b2  = (const float*)d_in[7];
    const float* ew_w      = (const float*)d_in[8];
    const float* ew_b      = (const float*)d_in[9];
    const float* cn_scale  = (const float*)d_in[10];
    const float* edge_w1   = (const float*)d_in[11];
    const float* edge_b1   = (const float*)d_in[12];
    const float* edge_w2   = (const float*)d_in[13];
    const float* edge_b2   = (const float*)d_in[14];
    const float* node_w1   = (const float*)d_in[15];
    const float* node_b1   = (const float*)d_in[16];
    const float* node_w2   = (const float*)d_in[17];
    const float* node_b2   = (const float*)d_in[18];
    const float* out_w     = (const float*)d_in[19];
    const float* out_b     = (const float*)d_in[20];
    const int* ei          = (const int*)d_in[21];
    const int* batch       = (const int*)d_in[22];
    const int* row = ei;
    const int* col = ei + NE;

    char* wp = (char*)d_ws;
    float* h32A   = (float*)wp; wp += (size_t)NN * 64 * 4;
    float* h32B   = (float*)wp; wp += (size_t)NN * 64 * 4;
    float* cA     = (float*)wp; wp += (size_t)NN * 3 * 4;
    float* cB     = (float*)wp; wp += (size_t)NN * 3 * 4;
    float* pooled = (float*)wp; wp += (size_t)NG * 64 * 4;
    float* cnt    = (float*)wp; wp += (size_t)NG * 4;
    _Float16* h16A = (_Float16*)wp; wp += (size_t)NN * 64 * 2;
    _Float16* h16B = (_Float16*)wp; wp += (size_t)NN * 64 * 2;
    _Float16* cw1T = (_Float16*)wp; wp += (size_t)NL * SEG0 * 2;
    _Float16* ew1T = (_Float16*)wp; wp += (size_t)NL * SEG1 * 2;
    _Float16* ew2T = (_Float16*)wp; wp += (size_t)NL * SEG2 * 2;
    _Float16* nw1T = (_Float16*)wp; wp += (size_t)NL * SEG3 * 2;
    _Float16* nw2T = (_Float16*)wp; wp += (size_t)NL * SEG4 * 2;
    _Float16* cw2T = (_Float16*)wp; wp += (size_t)NL * SEG5 * 2;
    // CSR region
    int* deg       = (int*)wp;    wp += (size_t)NN * 4;
    int* rowptr    = (int*)wp;    wp += (size_t)(NN + 4) * 4;
    int* pos       = (int*)wp;    wp += (size_t)NN * 4;
    int* bsum      = (int*)wp;    wp += (size_t)SCB * 4;
    int* rowP      = (int*)wp;    wp += (size_t)NE * 4;
    int* colP      = (int*)wp;    wp += (size_t)NE * 4;
    float4* deltas = (float4*)wp; wp += (size_t)NE * 16;
    size_t csr_need = (size_t)(wp - (char*)d_ws);
    float* agg = (float*)deg;  // legacy union
    bool use_csr = (ws_size >= csr_need);

    if (use_csr) {
        hipMemsetAsync(deg, 0, (size_t)NN * 4, stream);
        k_hist<<<(NE + 255) / 256, 256, 0, stream>>>(row, deg);
        k_scan_part<<<SCB, SCT, 0, stream>>>(deg, bsum);
        k_scan_mid<<<1, SCB, 0, stream>>>(bsum);
        k_scan_fin<<<SCB, SCT, 0, stream>>>(deg, bsum, rowptr);
        hipMemcpyAsync(pos, rowptr, (size_t)NN * 4, hipMemcpyDeviceToDevice, stream);
        k_scatter2<<<(NE + 255) / 256, 256, 0, stream>>>(row, col, pos, rowP, colP);
    }
    k_prep_all<<<(NL * SEGTOT + 255) / 256, 256, 0, stream>>>(
        coord_w1, edge_w1, edge_w2, node_w1, node_w2, coord_w2,
        cw1T, ew1T, ew2T, nw1T, nw2T, cw2T);
    k_init_h<<<(NN * 64 + 255) / 256, 256, 0, stream>>>(x, in_w, in_b, h32A, h16A);

    const float* c_cur = coords_in;
    float* c_nxt = cA;
    float* h32cur = h32A; float* h32nxt = h32B;
    _Float16* h16cur = h16A; _Float16* h16nxt = h16B;

    for (int l = 0; l < NL; ++l) {
        if (use_csr) {
            k_coord3<1><<<2048, 256, 0, stream>>>(h16cur, c_cur, nullptr, rowP, colP, deltas,
                cw1T + (size_t)l * SEG0, coord_b1 + l * 128,
                cw2T + (size_t)l * SEG5, coord_b2 + l * 3,
                ew_w + l * 3, ew_b + l, cn_scale + l);
            k_coord_apply<<<(NN + 255) / 256, 256, 0, stream>>>(c_cur, c_nxt, rowptr, deltas);
            k_edge_node<<<NT_N, 256, 0, stream>>>(h16cur, h32cur, h16nxt, h32nxt, c_nxt,
                rowP, colP, rowptr,
                ew1T + (size_t)l * SEG1, edge_b1 + l * 128,
                ew2T + (size_t)l * SEG2, edge_b2 + l * 64,
                nw1T + (size_t)l * SEG3, node_b1 + l * 128,
                nw2T + (size_t)l * SEG4, node_b2 + l * 64);
            { float* t = h32cur; h32cur = h32nxt; h32nxt = t; }
            { _Float16* t = h16cur; h16cur = h16nxt; h16nxt = t; }
        } else {
            hipMemcpyAsync(c_nxt, c_cur, (size_t)NN * 3 * sizeof(float), hipMemcpyDeviceToDevice, stream);
            k_coord3<0><<<2048, 256, 0, stream>>>(h16A, c_cur, c_nxt, row, col, nullptr,
                cw1T + (size_t)l * SEG0, coord_b1 + l * 128,
                cw2T + (size_t)l * SEG5, coord_b2 + l * 3,
                ew_w + l * 3, ew_b + l, cn_scale + l);
            hipMemsetAsync(agg, 0, (size_t)NN * 64 * 4, stream);
            k_edge_legacy<<<2048, 256, 0, stream>>>(h16A, c_nxt, agg, row, col,
                ew1T + (size_t)l * SEG1, edge_b1 + l * 128,
                ew2T + (size_t)l * SEG2, edge_b2 + l * 64);
            k_node_legacy<<<1024, 256, 0, stream>>>(h32A, h16A, agg,
                nw1T + (size_t)l * SEG3, node_b1 + l * 128,
                nw2T + (size_t)l * SEG4, node_b2 + l * 64);
        }
        { const float* t = c_cur; c_cur = c_nxt; c_nxt = (t == cA || t == coords_in) ? ((c_nxt == cA) ? cB : cA) : (float*)t; }
        if (c_nxt == c_cur) c_nxt = (c_cur == cA) ? cB : cA;  // safety
    }
    const float* hfinal = use_csr ? h32cur : h32A;
    hipMemsetAsync(pooled, 0, (size_t)(NG * 64 + NG) * sizeof(float), stream);
    k_pool_seg<<<512, 256, 0, stream>>>(hfinal, batch, pooled, cnt);
    k_final<<<NG, 128, 0, stream>>>(pooled, cnt, out_w, out_b, (float*)d_out);
}

// Round 9
// 1342.863 us; speedup vs baseline: 1.0879x; 1.0879x over previous
//
#include <hip/hip_runtime.h>
#include <math.h>

#define NN 100000
#define NE 1000000
#define NG 64
#define NL 4
#define NT_E (NE / 32)
#define NT_N (NN / 32)

typedef __attribute__((ext_vector_type(8))) _Float16 f16x8;
typedef __attribute__((ext_vector_type(4))) float f32x4;

#define MFMA16(a, b, c) __builtin_amdgcn_mfma_f32_16x16x32_f16(a, b, c, 0, 0, 0)
#define LOG2E 1.44269504088896340f
__device__ __forceinline__ float fsig_(float x) {
    return __builtin_amdgcn_rcpf(1.0f + __builtin_amdgcn_exp2f(-LOG2E * x));
}
__device__ __forceinline__ float fsilu_(float x) { return x * fsig_(x); }

// XOR-swizzled access into the [32][136] f16 inter-GEMM buffer.
// byte ^= ((row>>3)&3)<<5 : writeback (rows lg*4+j, cols 16-consecutive) hits all
// 32 banks 2-way (free); b128 A-frag reads balance to the 8-pass minimum.
// col*2 < 256 and xor of bits 5-6 stays < 256; 16B alignment preserved.
__device__ __forceinline__ _Float16* h1ptr(_Float16 (*h1)[136], int row, int col) {
    return (_Float16*)((char*)&h1[0][0] + row * 272 +
                       ((col * 2) ^ ((((unsigned)row >> 3) & 3) << 5)));
}

__global__ void k_init_h(const float* __restrict__ x, const float* __restrict__ in_w,
                         const float* __restrict__ in_b, float* __restrict__ h32,
                         _Float16* __restrict__ h16) {
    int idx = blockIdx.x * blockDim.x + threadIdx.x;
    if (idx >= NN * 64) return;
    int n = idx >> 6, j = idx & 63;
    float v = fmaf(x[n], in_w[j], in_b[j]);
    h32[idx] = v;
    h16[idx] = (_Float16)v;
}

// transpose + fp16 + zero-pad all weight families x 4 layers
#define SEG0 21504  // 128*168 cw1T
#define SEG1 21504  // ew1T
#define SEG2 8704   // 64*136  ew2T
#define SEG3 17408  // 128*136 nw1T
#define SEG4 8704   // nw2T
#define SEG5 2176   // 16*136  cw2T (O=3 padded to 16)
#define SEGTOT (SEG0 + SEG1 + SEG2 + SEG3 + SEG4 + SEG5)
__global__ void k_prep_all(const float* __restrict__ cw1, const float* __restrict__ ew1,
                           const float* __restrict__ ew2, const float* __restrict__ nw1,
                           const float* __restrict__ nw2, const float* __restrict__ cw2,
                           _Float16* __restrict__ cw1T, _Float16* __restrict__ ew1T,
                           _Float16* __restrict__ ew2T, _Float16* __restrict__ nw1T,
                           _Float16* __restrict__ nw2T, _Float16* __restrict__ cw2T) {
    int i = blockIdx.x * blockDim.x + threadIdx.x;
    if (i >= NL * SEGTOT) return;
    int l = i / SEGTOT, r = i - l * SEGTOT;
    const float* src; _Float16* dst; int K, O, SD, j;
    if (r < SEG0) { src = cw1 + (size_t)l * 131 * 128; dst = cw1T + (size_t)l * SEG0; K = 131; O = 128; SD = 168; j = r; }
    else if ((r -= SEG0) < SEG1) { src = ew1 + (size_t)l * 131 * 128; dst = ew1T + (size_t)l * SEG1; K = 131; O = 128; SD = 168; j = r; }
    else if ((r -= SEG1) < SEG2) { src = ew2 + (size_t)l * 128 * 64; dst = ew2T + (size_t)l * SEG2; K = 128; O = 64; SD = 136; j = r; }
    else if ((r -= SEG2) < SEG3) { src = nw1 + (size_t)l * 128 * 128; dst = nw1T + (size_t)l * SEG3; K = 128; O = 128; SD = 136; j = r; }
    else if ((r -= SEG3) < SEG4) { src = nw2 + (size_t)l * 128 * 64; dst = nw2T + (size_t)l * SEG4; K = 128; O = 64; SD = 136; j = r; }
    else {
        r -= SEG4;
        const float* s2 = cw2 + (size_t)l * 128 * 3;
        int o = r / 136, k = r - o * 136;
        cw2T[(size_t)l * SEG5 + r] = (o < 3 && k < 128) ? (_Float16)s2[(size_t)k * 3 + o] : (_Float16)0.0f;
        return;
    }
    int o = j / SD, k = j - o * SD;
    dst[j] = (k < K) ? (_Float16)src[(size_t)k * O + o] : (_Float16)0.0f;
}

// ---- CSR build ----
__global__ void k_hist(const int* __restrict__ row, int* __restrict__ deg) {
    int e = blockIdx.x * blockDim.x + threadIdx.x;
    if (e < NE) atomicAdd(&deg[row[e]], 1);
}
#define SCB 256
#define SCT 256
#define SCCH ((NN + SCB - 1) / SCB)
__global__ void k_scan_part(const int* __restrict__ deg, int* __restrict__ bsum) {
    __shared__ int red[SCT];
    int b = blockIdx.x;
    int s = b * SCCH, e = min(NN, s + SCCH);
    int sum = 0;
    for (int i = s + threadIdx.x; i < e; i += SCT) sum += deg[i];
    red[threadIdx.x] = sum;
    __syncthreads();
    for (int off = SCT / 2; off > 0; off >>= 1) {
        if (threadIdx.x < off) red[threadIdx.x] += red[threadIdx.x + off];
        __syncthreads();
    }
    if (threadIdx.x == 0) bsum[b] = red[0];
}
__global__ void k_scan_mid(int* __restrict__ bsum) {
    __shared__ int ss[SCB];
    int t = threadIdx.x;
    ss[t] = bsum[t];
    __syncthreads();
    if (t == 0) {
        int run = 0;
        for (int i = 0; i < SCB; ++i) { int v = ss[i]; ss[i] = run; run += v; }
    }
    __syncthreads();
    bsum[t] = ss[t];
}
__global__ void k_scan_fin(const int* __restrict__ deg, const int* __restrict__ bsum,
                           int* __restrict__ rowptr) {
    __shared__ int tsum[SCT];
    int b = blockIdx.x;
    int s = b * SCCH, e = min(NN, s + SCCH);
    const int per = (SCCH + SCT - 1) / SCT;
    int ts = s + threadIdx.x * per;
    int te = min(e, ts + per);
    int sum = 0;
    for (int i = ts; i < te; ++i) sum += deg[i];
    tsum[threadIdx.x] = sum;
    __syncthreads();
    if (threadIdx.x == 0) {
        int run = bsum[b];
        for (int i = 0; i < SCT; ++i) { int v = tsum[i]; tsum[i] = run; run += v; }
    }
    __syncthreads();
    int run = tsum[threadIdx.x];
    for (int i = ts; i < te; ++i) { rowptr[i] = run; run += deg[i]; }
    if (b == 0 && threadIdx.x == 0) rowptr[NN] = NE;
}
__global__ void k_scatter2(const int* __restrict__ row, const int* __restrict__ col,
                           int* __restrict__ pos, int* __restrict__ rowP,
                           int* __restrict__ colP) {
    int e = blockIdx.x * blockDim.x + threadIdx.x;
    if (e < NE) {
        int r = row[e];
        int p = atomicAdd(&pos[r], 1);
        rowP[p] = r;
        colP[p] = col[e];
    }
}

// ---- coord: block-coop GEMM1 + ks-split GEMM2; CSR=1 -> write deltas[slot]
template <int CSR>
__global__ __launch_bounds__(256)
void k_coord3(const _Float16* __restrict__ h16,
              const float* __restrict__ ccur, float* __restrict__ cnext,
              const int* __restrict__ rowP, const int* __restrict__ colP,
              float4* __restrict__ deltas,
              const _Float16* __restrict__ w1T, const float* __restrict__ b1,
              const _Float16* __restrict__ w2T, const float* __restrict__ b2,
              const float* __restrict__ eww, const float* __restrict__ ewb,
              const float* __restrict__ cns) {
    __shared__ __attribute__((aligned(16))) _Float16 cin[32][168];
    __shared__ __attribute__((aligned(16))) _Float16 h1[32][136];
    __shared__ __attribute__((aligned(16))) float pbuf[4][32][17];
    __shared__ float gate[32];
    for (int i = threadIdx.x; i < 32 * 168; i += 256) (&cin[0][0])[i] = (_Float16)0.0f;
    int tid = threadIdx.x;
    int w = tid >> 6, lane = tid & 63, lc = lane & 15, lg = lane >> 4;
    float e0w = eww[0], e1w = eww[1], e2w = eww[2], ebw = ewb[0], sc = cns[0];
    float b20 = b2[0], b21 = b2[1], b22 = b2[2];
    f16x8 bw1[2][5];
#pragma unroll
    for (int ti = 0; ti < 2; ++ti)
#pragma unroll
        for (int ks = 0; ks < 5; ++ks)
            bw1[ti][ks] = *(const f16x8*)&w1T[(size_t)((2 * w + ti) * 16 + lc) * 168 + ks * 32 + lg * 8];
    f16x8 bw2 = *(const f16x8*)&w2T[(size_t)lc * 136 + w * 32 + lg * 8];
    float bias10 = b1[(2 * w) * 16 + lc], bias11 = b1[(2 * w + 1) * 16 + lc];
    __syncthreads();

    for (int tile = blockIdx.x; tile < NT_E; tile += gridDim.x) {
        int e0 = tile * 32;
        {
            int el = tid >> 3, part = tid & 7;
            int r = rowP[e0 + el], c = colP[e0 + el];
            *(f16x8*)&cin[el][part * 8] = *(const f16x8*)&h16[(size_t)r * 64 + part * 8];
            *(f16x8*)&cin[el][64 + part * 8] = *(const f16x8*)&h16[(size_t)c * 64 + part * 8];
        }
        if (tid < 32) {
            int r = rowP[e0 + tid], c = colP[e0 + tid];
            float rx = ccur[r * 3 + 0] - ccur[c * 3 + 0];
            float ry = ccur[r * 3 + 1] - ccur[c * 3 + 1];
            float rz = ccur[r * 3 + 2] - ccur[c * 3 + 2];
            cin[tid][128] = (_Float16)rx; cin[tid][129] = (_Float16)ry; cin[tid][130] = (_Float16)rz;
            gate[tid] = fsig_(fmaf(rx, e0w, fmaf(ry, e1w, fmaf(rz, e2w, ebw))));
        }
        __syncthreads();
        f32x4 acc[2][2];
        acc[0][0] = acc[0][1] = acc[1][0] = acc[1][1] = (f32x4){0.f, 0.f, 0.f, 0.f};
#pragma unroll
        for (int ks = 0; ks < 5; ++ks) {
            f16x8 a0 = *(const f16x8*)&cin[lc][ks * 32 + lg * 8];
            f16x8 a1 = *(const f16x8*)&cin[16 + lc][ks * 32 + lg * 8];
#pragma unroll
            for (int ti = 0; ti < 2; ++ti) {
                acc[0][ti] = MFMA16(a0, bw1[ti][ks], acc[0][ti]);
                acc[1][ti] = MFMA16(a1, bw1[ti][ks], acc[1][ti]);
            }
        }
#pragma unroll
        for (int ti = 0; ti < 2; ++ti) {
            int colc = (2 * w + ti) * 16 + lc;
            float bias = ti ? bias11 : bias10;
#pragma unroll
            for (int rt = 0; rt < 2; ++rt)
#pragma unroll
                for (int j = 0; j < 4; ++j)
                    *h1ptr(h1, rt * 16 + lg * 4 + j, colc) = (_Float16)fsilu_(acc[rt][ti][j] + bias);
        }
        __syncthreads();
        f32x4 c2[2];
        c2[0] = c2[1] = (f32x4){0.f, 0.f, 0.f, 0.f};
        {
            f16x8 a0 = *(const f16x8*)h1ptr(h1, lc, w * 32 + lg * 8);
            f16x8 a1 = *(const f16x8*)h1ptr(h1, 16 + lc, w * 32 + lg * 8);
            c2[0] = MFMA16(a0, bw2, c2[0]);
            c2[1] = MFMA16(a1, bw2, c2[1]);
        }
#pragma unroll
        for (int rt = 0; rt < 2; ++rt)
#pragma unroll
            for (int j = 0; j < 4; ++j)
                pbuf[w][rt * 16 + lg * 4 + j][lc] = c2[rt][j];
        __syncthreads();
        if (tid < 32) {
            float d0 = pbuf[0][tid][0] + pbuf[1][tid][0] + pbuf[2][tid][0] + pbuf[3][tid][0] + b20;
            float d1 = pbuf[0][tid][1] + pbuf[1][tid][1] + pbuf[2][tid][1] + pbuf[3][tid][1] + b21;
            float d2 = pbuf[0][tid][2] + pbuf[1][tid][2] + pbuf[2][tid][2] + pbuf[3][tid][2] + b22;
            float ss = d0 * d0 + d1 * d1 + d2 * d2;
            float nrm = fmaxf(__builtin_amdgcn_sqrtf(ss), 1e-8f);
            float m = sc * __builtin_amdgcn_rcpf(nrm) * gate[tid];
            if (CSR) {
                deltas[e0 + tid] = make_float4(d0 * m, d1 * m, d2 * m, 0.0f);
            } else {
                int r = rowP[e0 + tid];
                atomicAdd(&cnext[(size_t)r * 3 + 0], d0 * m);
                atomicAdd(&cnext[(size_t)r * 3 + 1], d1 * m);
                atomicAdd(&cnext[(size_t)r * 3 + 2], d2 * m);
            }
        }
    }
}

__global__ void k_coord_apply(const float* __restrict__ ccur, float* __restrict__ cnext,
                              const int* __restrict__ rowptr,
                              const float4* __restrict__ deltas) {
    int n = blockIdx.x * blockDim.x + threadIdx.x;
    if (n >= NN) return;
    int s = rowptr[n], e = rowptr[n + 1];
    float d0 = 0.f, d1 = 0.f, d2 = 0.f;
    for (int j = s; j < e; ++j) {
        float4 d = deltas[j];
        d0 += d.x; d1 += d.y; d2 += d.z;
    }
    cnext[(size_t)n * 3 + 0] = ccur[(size_t)n * 3 + 0] + d0;
    cnext[(size_t)n * 3 + 1] = ccur[(size_t)n * 3 + 1] + d1;
    cnext[(size_t)n * 3 + 2] = ccur[(size_t)n * 3 + 2] + d2;
}

// ---- edge: CSR=1 -> write emsgS[slot] coalesced; CSR=0 -> atomic agg
template <int CSR>
__global__ __launch_bounds__(256)
void k_edge3(const _Float16* __restrict__ h16, const float* __restrict__ coords,
             float* __restrict__ agg, _Float16* __restrict__ emsgS,
             const int* __restrict__ rowP, const int* __restrict__ colP,
             const _Float16* __restrict__ w1T, const float* __restrict__ b1,
             const _Float16* __restrict__ w2T, const float* __restrict__ b2) {
    __shared__ __attribute__((aligned(16))) _Float16 cin[32][168];
    __shared__ __attribute__((aligned(16))) _Float16 h1[32][136];
    __shared__ __attribute__((aligned(16))) _Float16 msg[32][72];
    for (int i = threadIdx.x; i < 32 * 168; i += 256) (&cin[0][0])[i] = (_Float16)0.0f;
    int tid = threadIdx.x;
    int w = tid >> 6, lane = tid & 63, lc = lane & 15, lg = lane >> 4;
    f16x8 bw1[2][5];
#pragma unroll
    for (int ti = 0; ti < 2; ++ti)
#pragma unroll
        for (int ks = 0; ks < 5; ++ks)
            bw1[ti][ks] = *(const f16x8*)&w1T[(size_t)((2 * w + ti) * 16 + lc) * 168 + ks * 32 + lg * 8];
    f16x8 bw2[4];
#pragma unroll
    for (int ks = 0; ks < 4; ++ks)
        bw2[ks] = *(const f16x8*)&w2T[(size_t)(w * 16 + lc) * 136 + ks * 32 + lg * 8];
    float bias10 = b1[(2 * w) * 16 + lc], bias11 = b1[(2 * w + 1) * 16 + lc];
    float bias2 = b2[w * 16 + lc];
    __syncthreads();

    for (int tile = blockIdx.x; tile < NT_E; tile += gridDim.x) {
        int e0 = tile * 32;
        {
            int el = tid >> 3, part = tid & 7;
            int r = rowP[e0 + el], c = colP[e0 + el];
            *(f16x8*)&cin[el][part * 8] = *(const f16x8*)&h16[(size_t)r * 64 + part * 8];
            *(f16x8*)&cin[el][64 + part * 8] = *(const f16x8*)&h16[(size_t)c * 64 + part * 8];
        }
        if (tid < 32) {
            int r = rowP[e0 + tid], c = colP[e0 + tid];
            cin[tid][128] = (_Float16)(coords[r * 3 + 0] - coords[c * 3 + 0]);
            cin[tid][129] = (_Float16)(coords[r * 3 + 1] - coords[c * 3 + 1]);
            cin[tid][130] = (_Float16)(coords[r * 3 + 2] - coords[c * 3 + 2]);
        }
        __syncthreads();
        f32x4 acc[2][2];
        acc[0][0] = acc[0][1] = acc[1][0] = acc[1][1] = (f32x4){0.f, 0.f, 0.f, 0.f};
#pragma unroll
        for (int ks = 0; ks < 5; ++ks) {
            f16x8 a0 = *(const f16x8*)&cin[lc][ks * 32 + lg * 8];
            f16x8 a1 = *(const f16x8*)&cin[16 + lc][ks * 32 + lg * 8];
#pragma unroll
            for (int ti = 0; ti < 2; ++ti) {
                acc[0][ti] = MFMA16(a0, bw1[ti][ks], acc[0][ti]);
                acc[1][ti] = MFMA16(a1, bw1[ti][ks], acc[1][ti]);
            }
        }
#pragma unroll
        for (int ti = 0; ti < 2; ++ti) {
            int colc = (2 * w + ti) * 16 + lc;
            float bias = ti ? bias11 : bias10;
#pragma unroll
            for (int rt = 0; rt < 2; ++rt)
#pragma unroll
                for (int j = 0; j < 4; ++j)
                    *h1ptr(h1, rt * 16 + lg * 4 + j, colc) = (_Float16)fsilu_(acc[rt][ti][j] + bias);
        }
        __syncthreads();
        f32x4 c2[2];
        c2[0] = c2[1] = (f32x4){0.f, 0.f, 0.f, 0.f};
#pragma unroll
        for (int ks = 0; ks < 4; ++ks) {
            f16x8 a0 = *(const f16x8*)h1ptr(h1, lc, ks * 32 + lg * 8);
            f16x8 a1 = *(const f16x8*)h1ptr(h1, 16 + lc, ks * 32 + lg * 8);
            c2[0] = MFMA16(a0, bw2[ks], c2[0]);
            c2[1] = MFMA16(a1, bw2[ks], c2[1]);
        }
        if (CSR) {
#pragma unroll
            for (int rt = 0; rt < 2; ++rt)
#pragma unroll
                for (int j = 0; j < 4; ++j)
                    msg[rt * 16 + lg * 4 + j][w * 16 + lc] = (_Float16)fsilu_(c2[rt][j] + bias2);
            __syncthreads();
            int r = tid >> 3, part = tid & 7;
            *(f16x8*)&emsgS[(size_t)(e0 + r) * 64 + part * 8] = *(const f16x8*)&msg[r][part * 8];
        } else {
#pragma unroll
            for (int rt = 0; rt < 2; ++rt)
#pragma unroll
                for (int j = 0; j < 4; ++j)
                    atomicAdd(&agg[(size_t)rowP[e0 + rt * 16 + lg * 4 + j] * 64 + w * 16 + lc],
                              fsilu_(c2[rt][j] + bias2));
            __syncthreads();
        }
    }
}

// ---- node: CSR=1 -> contiguous emsgS range per node; else agg read
template <int CSR>
__global__ __launch_bounds__(256)
void k_node3(float* __restrict__ h32, _Float16* __restrict__ h16,
             const float* __restrict__ agg, const _Float16* __restrict__ emsgS,
             const int* __restrict__ rowptr,
             const _Float16* __restrict__ w1T, const float* __restrict__ b1,
             const _Float16* __restrict__ w2T, const float* __restrict__ b2) {
    __shared__ __attribute__((aligned(16))) _Float16 cin[32][136];
    __shared__ __attribute__((aligned(16))) _Float16 h1[32][136];
    __shared__ __attribute__((aligned(16))) float vbuf[32][64];
    int tid = threadIdx.x;
    int w = tid >> 6, lane = tid & 63, lc = lane & 15, lg = lane >> 4;
    f16x8 bw1[2][4], bw2[4];
#pragma unroll
    for (int ti = 0; ti < 2; ++ti)
#pragma unroll
        for (int ks = 0; ks < 4; ++ks)
            bw1[ti][ks] = *(const f16x8*)&w1T[(size_t)((2 * w + ti) * 16 + lc) * 136 + ks * 32 + lg * 8];
#pragma unroll
    for (int ks = 0; ks < 4; ++ks)
        bw2[ks] = *(const f16x8*)&w2T[(size_t)(w * 16 + lc) * 136 + ks * 32 + lg * 8];
    float bias10 = b1[(2 * w) * 16 + lc], bias11 = b1[(2 * w + 1) * 16 + lc];
    float bias2 = b2[w * 16 + lc];

    for (int tile = blockIdx.x; tile < NT_N; tile += gridDim.x) {
        int n0 = tile * 32;
        {
            int nl = tid >> 3, part = tid & 7;
            int n = n0 + nl;
            *(f16x8*)&cin[nl][part * 8] = *(const f16x8*)&h16[(size_t)n * 64 + part * 8];
            if (CSR) {
                float a[8] = {0.f, 0.f, 0.f, 0.f, 0.f, 0.f, 0.f, 0.f};
                int s = rowptr[n], e = rowptr[n + 1];
                for (int jj = s; jj < e; ++jj) {
                    f16x8 m = *(const f16x8*)&emsgS[(size_t)jj * 64 + part * 8];
#pragma unroll
                    for (int q = 0; q < 8; ++q) a[q] += (float)m[q];
                }
                f16x8 o;
#pragma unroll
                for (int q = 0; q < 8; ++q) o[q] = (_Float16)a[q];
                *(f16x8*)&cin[nl][64 + part * 8] = o;
            } else {
                f32x4 xx = *(const f32x4*)&agg[(size_t)n * 64 + part * 8];
                f32x4 yy = *(const f32x4*)&agg[(size_t)n * 64 + part * 8 + 4];
                f16x8 o;
                o[0] = (_Float16)xx[0]; o[1] = (_Float16)xx[1]; o[2] = (_Float16)xx[2]; o[3] = (_Float16)xx[3];
                o[4] = (_Float16)yy[0]; o[5] = (_Float16)yy[1]; o[6] = (_Float16)yy[2]; o[7] = (_Float16)yy[3];
                *(f16x8*)&cin[nl][64 + part * 8] = o;
            }
        }
        __syncthreads();
        f32x4 acc[2][2];
        acc[0][0] = acc[0][1] = acc[1][0] = acc[1][1] = (f32x4){0.f, 0.f, 0.f, 0.f};
#pragma unroll
        for (int ks = 0; ks < 4; ++ks) {
            f16x8 a0 = *(const f16x8*)&cin[lc][ks * 32 + lg * 8];
            f16x8 a1 = *(const f16x8*)&cin[16 + lc][ks * 32 + lg * 8];
#pragma unroll
            for (int ti = 0; ti < 2; ++ti) {
                acc[0][ti] = MFMA16(a0, bw1[ti][ks], acc[0][ti]);
                acc[1][ti] = MFMA16(a1, bw1[ti][ks], acc[1][ti]);
            }
        }
#pragma unroll
        for (int ti = 0; ti < 2; ++ti) {
            int colc = (2 * w + ti) * 16 + lc;
            float bias = ti ? bias11 : bias10;
#pragma unroll
            for (int rt = 0; rt < 2; ++rt)
#pragma unroll
                for (int j = 0; j < 4; ++j)
                    *h1ptr(h1, rt * 16 + lg * 4 + j, colc) = (_Float16)fsilu_(acc[rt][ti][j] + bias);
        }
        __syncthreads();
        f32x4 c2[2];
        c2[0] = c2[1] = (f32x4){0.f, 0.f, 0.f, 0.f};
#pragma unroll
        for (int ks = 0; ks < 4; ++ks) {
            f16x8 a0 = *(const f16x8*)h1ptr(h1, lc, ks * 32 + lg * 8);
            f16x8 a1 = *(const f16x8*)h1ptr(h1, 16 + lc, ks * 32 + lg * 8);
            c2[0] = MFMA16(a0, bw2[ks], c2[0]);
            c2[1] = MFMA16(a1, bw2[ks], c2[1]);
        }
#pragma unroll
        for (int rt = 0; rt < 2; ++rt)
#pragma unroll
            for (int j = 0; j < 4; ++j) {
                int rl = rt * 16 + lg * 4 + j, colc = w * 16 + lc;
                vbuf[rl][colc] = h32[(size_t)(n0 + rl) * 64 + colc] + c2[rt][j] + bias2;
            }
        __syncthreads();
        {
            int r = w * 8 + (lane >> 3), sub = lane & 7;
            f32x4 v0 = *(const f32x4*)&vbuf[r][sub * 8];
            f32x4 v1 = *(const f32x4*)&vbuf[r][sub * 8 + 4];
            float s = v0[0] + v0[1] + v0[2] + v0[3] + v1[0] + v1[1] + v1[2] + v1[3];
            float sq = v0[0]*v0[0] + v0[1]*v0[1] + v0[2]*v0[2] + v0[3]*v0[3]
                     + v1[0]*v1[0] + v1[1]*v1[1] + v1[2]*v1[2] + v1[3]*v1[3];
            s += __shfl_xor(s, 1); s += __shfl_xor(s, 2); s += __shfl_xor(s, 4);
            sq += __shfl_xor(sq, 1); sq += __shfl_xor(sq, 2); sq += __shfl_xor(sq, 4);
            float mu = s * (1.0f / 64.0f);
            float var = sq * (1.0f / 64.0f) - mu * mu;
            float rs = __builtin_amdgcn_rcpf(__builtin_amdgcn_sqrtf(var + 1e-5f));
            size_t base = (size_t)(n0 + r) * 64 + sub * 8;
            f32x4 o0, o1; f16x8 oh;
#pragma unroll
            for (int i = 0; i < 4; ++i) {
                o0[i] = (v0[i] - mu) * rs;
                o1[i] = (v1[i] - mu) * rs;
                oh[i] = (_Float16)o0[i];
                oh[4 + i] = (_Float16)o1[i];
            }
            *(f32x4*)&h32[base] = o0;
            *(f32x4*)&h32[base + 4] = o1;
            *(f16x8*)&h16[base] = oh;
        }
        __syncthreads();
    }
}

__global__ void k_pool_seg(const float* __restrict__ h, const int* __restrict__ batch,
                           float* __restrict__ pooled, float* __restrict__ cnt) {
    int lane = threadIdx.x & 63;
    int wid = blockIdx.x * (blockDim.x >> 6) + (threadIdx.x >> 6);
    int nwav = gridDim.x * (blockDim.x >> 6);
    int chunk = (NN + nwav - 1) / nwav;
    int s = wid * chunk;
    if (s >= NN) return;
    int e = s + chunk; if (e > NN) e = NN;
    int g = batch[s];
    float acc = 0.0f, c = 0.0f;
    for (int n = s; n < e; ++n) {
        int b = batch[n];
        if (b != g) {
            atomicAdd(&pooled[g * 64 + lane], acc);
            if (lane == 0) atomicAdd(&cnt[g], c);
            acc = 0.0f; c = 0.0f; g = b;
        }
        acc += h[(size_t)n * 64 + lane];
        c += 1.0f;
    }
    atomicAdd(&pooled[g * 64 + lane], acc);
    if (lane == 0) atomicAdd(&cnt[g], c);
}

__global__ void k_final(const float* __restrict__ pooled, const float* __restrict__ cnt,
                        const float* __restrict__ ow, const float* __restrict__ ob,
                        float* __restrict__ out) {
    __shared__ float red[2];
    int g = blockIdx.x, o = threadIdx.x;
    float c = fmaxf(cnt[g], 1.0f);
    float acc = ob[o];
#pragma unroll
    for (int j = 0; j < 64; ++j) {
        float pm = fmaxf(pooled[g * 64 + j] / c, 0.0f);
        acc = fmaf(pm, ow[j * 128 + o], acc);
    }
    float ss = acc * acc;
#pragma unroll
    for (int off = 32; off > 0; off >>= 1) ss += __shfl_xor(ss, off);
    if ((o & 63) == 0) red[o >> 6] = ss;
    __syncthreads();
    float nrm = sqrtf(red[0] + red[1]);
    out[g * 128 + o] = acc / fmaxf(nrm, 1e-12f);
}

extern "C" void kernel_launch(void* const* d_in, const int* in_sizes, int n_in,
                              void* d_out, int out_size, void* d_ws, size_t ws_size,
                              hipStream_t stream) {
    const float* x         = (const float*)d_in[0];
    const float* coords_in = (const float*)d_in[1];
    const float* in_w      = (const float*)d_in[2];
    const float* in_b      = (const float*)d_in[3];
    const float* coord_w1  = (const float*)d_in[4];
    const float* coord_b1  = (const float*)d_in[5];
    const float* coord_w2  = (const float*)d_in[6];
    const float* coord_b2  = (const float*)d_in[7];
    const float* ew_w      = (const float*)d_in[8];
    const float* ew_b      = (const float*)d_in[9];
    const float* cn_scale  = (const float*)d_in[10];
    const float* edge_w1   = (const float*)d_in[11];
    const float* edge_b1   = (const float*)d_in[12];
    const float* edge_w2   = (const float*)d_in[13];
    const float* edge_b2   = (const float*)d_in[14];
    const float* node_w1   = (const float*)d_in[15];
    const float* node_b1   = (const float*)d_in[16];
    const float* node_w2   = (const float*)d_in[17];
    const float* node_b2   = (const float*)d_in[18];
    const float* out_w     = (const float*)d_in[19];
    const float* out_b     = (const float*)d_in[20];
    const int* ei          = (const int*)d_in[21];
    const int* batch       = (const int*)d_in[22];
    const int* row = ei;
    const int* col = ei + NE;

    char* wp = (char*)d_ws;
    float* h32    = (float*)wp; wp += (size_t)NN * 64 * 4;
    float* cA     = (float*)wp; wp += (size_t)NN * 3 * 4;
    float* cB     = (float*)wp; wp += (size_t)NN * 3 * 4;
    float* pooled = (float*)wp; wp += (size_t)NG * 64 * 4;
    float* cnt    = (float*)wp; wp += (size_t)NG * 4;
    _Float16* h16  = (_Float16*)wp; wp += (size_t)NN * 64 * 2;
    _Float16* cw1T = (_Float16*)wp; wp += (size_t)NL * SEG0 * 2;
    _Float16* ew1T = (_Float16*)wp; wp += (size_t)NL * SEG1 * 2;
    _Float16* ew2T = (_Float16*)wp; wp += (size_t)NL * SEG2 * 2;
    _Float16* nw1T = (_Float16*)wp; wp += (size_t)NL * SEG3 * 2;
    _Float16* nw2T = (_Float16*)wp; wp += (size_t)NL * SEG4 * 2;
    _Float16* cw2T = (_Float16*)wp; wp += (size_t)NL * SEG5 * 2;
    // CSR region
    int* deg       = (int*)wp;            wp += (size_t)NN * 4;
    int* rowptr    = (int*)wp;            wp += (size_t)(NN + 4) * 4;
    int* pos       = (int*)wp;            wp += (size_t)NN * 4;
    int* bsum      = (int*)wp;            wp += (size_t)SCB * 4;
    int* rowP      = (int*)wp;            wp += (size_t)NE * 4;
    int* colP      = (int*)wp;            wp += (size_t)NE * 4;
    float4* deltas = (float4*)wp;         wp += (size_t)NE * 16;
    _Float16* emsgS= (_Float16*)wp;       wp += (size_t)NE * 64 * 2;
    size_t csr_need = (size_t)(wp - (char*)d_ws);
    float* agg = (float*)deg;  // legacy path union
    bool use_csr = (ws_size >= csr_need);

    if (use_csr) {
        hipMemsetAsync(deg, 0, (size_t)NN * 4, stream);
        k_hist<<<(NE + 255) / 256, 256, 0, stream>>>(row, deg);
        k_scan_part<<<SCB, SCT, 0, stream>>>(deg, bsum);
        k_scan_mid<<<1, SCB, 0, stream>>>(bsum);
        k_scan_fin<<<SCB, SCT, 0, stream>>>(deg, bsum, rowptr);
        hipMemcpyAsync(pos, rowptr, (size_t)NN * 4, hipMemcpyDeviceToDevice, stream);
        k_scatter2<<<(NE + 255) / 256, 256, 0, stream>>>(row, col, pos, rowP, colP);
    }
    k_prep_all<<<(NL * SEGTOT + 255) / 256, 256, 0, stream>>>(
        coord_w1, edge_w1, edge_w2, node_w1, node_w2, coord_w2,
        cw1T, ew1T, ew2T, nw1T, nw2T, cw2T);
    k_init_h<<<(NN * 64 + 255) / 256, 256, 0, stream>>>(x, in_w, in_b, h32, h16);

    const float* cur = coords_in;
    float* nxt = cA;
    for (int l = 0; l < NL; ++l) {
        if (use_csr) {
            k_coord3<1><<<3125, 256, 0, stream>>>(h16, cur, nullptr, rowP, colP, deltas,
                cw1T + (size_t)l * SEG0, coord_b1 + l * 128,
                cw2T + (size_t)l * SEG5, coord_b2 + l * 3,
                ew_w + l * 3, ew_b + l, cn_scale + l);
            k_coord_apply<<<(NN + 255) / 256, 256, 0, stream>>>(cur, nxt, rowptr, deltas);
            k_edge3<1><<<3125, 256, 0, stream>>>(h16, nxt, nullptr, emsgS, rowP, colP,
                ew1T + (size_t)l * SEG1, edge_b1 + l * 128,
                ew2T + (size_t)l * SEG2, edge_b2 + l * 64);
            k_node3<1><<<1563, 256, 0, stream>>>(h32, h16, nullptr, emsgS, rowptr,
                nw1T + (size_t)l * SEG3, node_b1 + l * 128,
                nw2T + (size_t)l * SEG4, node_b2 + l * 64);
        } else {
            hipMemcpyAsync(nxt, cur, (size_t)NN * 3 * sizeof(float), hipMemcpyDeviceToDevice, stream);
            k_coord3<0><<<2048, 256, 0, stream>>>(h16, cur, nxt, row, col, nullptr,
                cw1T + (size_t)l * SEG0, coord_b1 + l * 128,
                cw2T + (size_t)l * SEG5, coord_b2 + l * 3,
                ew_w + l * 3, ew_b + l, cn_scale + l);
            hipMemsetAsync(agg, 0, (size_t)NN * 64 * 4, stream);
            k_edge3<0><<<2048, 256, 0, stream>>>(h16, nxt, agg, nullptr, row, col,
                ew1T + (size_t)l * SEG1, edge_b1 + l * 128,
                ew2T + (size_t)l * SEG2, edge_b2 + l * 64);
            k_node3<0><<<1024, 256, 0, stream>>>(h32, h16, agg, nullptr, nullptr,
                nw1T + (size_t)l * SEG3, node_b1 + l * 128,
                nw2T + (size_t)l * SEG4, node_b2 + l * 64);
        }
        cur = nxt;
        nxt = (nxt == cA) ? cB : cA;
    }
    hipMemsetAsync(pooled, 0, (size_t)(NG * 64 + NG) * sizeof(float), stream);
    k_pool_seg<<<512, 256, 0, stream>>>(h32, batch, pooled, cnt);
    k_final<<<NG, 128, 0, stream>>>(pooled, cnt, out_w, out_b, (float*)d_out);
}

// Round 10
// 1202.068 us; speedup vs baseline: 1.2153x; 1.1171x over previous
//
#include <hip/hip_runtime.h>
#include <math.h>

#define NN 100000
#define NE 1000000
#define NG 64
#define NL 4
#define NT_E (NE / 32)
#define NT_N (NN / 32)

typedef __attribute__((ext_vector_type(8))) _Float16 f16x8;
typedef __attribute__((ext_vector_type(4))) float f32x4;

#define MFMA16(a, b, c) __builtin_amdgcn_mfma_f32_16x16x32_f16(a, b, c, 0, 0, 0)
#define LOG2E 1.44269504088896340f
__device__ __forceinline__ float fsig_(float x) {
    return __builtin_amdgcn_rcpf(1.0f + __builtin_amdgcn_exp2f(-LOG2E * x));
}
__device__ __forceinline__ float fsilu_(float x) { return x * fsig_(x); }

__global__ void k_init_h(const float* __restrict__ x, const float* __restrict__ in_w,
                         const float* __restrict__ in_b, float* __restrict__ h32,
                         _Float16* __restrict__ h16) {
    int idx = blockIdx.x * blockDim.x + threadIdx.x;
    if (idx >= NN * 64) return;
    int n = idx >> 6, j = idx & 63;
    float v = fmaf(x[n], in_w[j], in_b[j]);
    h32[idx] = v;
    h16[idx] = (_Float16)v;
}

// transpose + fp16 + zero-pad all weight families x 4 layers
#define SEG0 21504  // 128*168 cw1T
#define SEG1 21504  // ew1T
#define SEG2 8704   // 64*136  ew2T
#define SEG3 17408  // 128*136 nw1T
#define SEG4 8704   // nw2T
#define SEG5 2176   // 16*136  cw2T (O=3 padded to 16)
#define SEGTOT (SEG0 + SEG1 + SEG2 + SEG3 + SEG4 + SEG5)
__global__ void k_prep_all(const float* __restrict__ cw1, const float* __restrict__ ew1,
                           const float* __restrict__ ew2, const float* __restrict__ nw1,
                           const float* __restrict__ nw2, const float* __restrict__ cw2,
                           _Float16* __restrict__ cw1T, _Float16* __restrict__ ew1T,
                           _Float16* __restrict__ ew2T, _Float16* __restrict__ nw1T,
                           _Float16* __restrict__ nw2T, _Float16* __restrict__ cw2T) {
    int i = blockIdx.x * blockDim.x + threadIdx.x;
    if (i >= NL * SEGTOT) return;
    int l = i / SEGTOT, r = i - l * SEGTOT;
    const float* src; _Float16* dst; int K, O, SD, j;
    if (r < SEG0) { src = cw1 + (size_t)l * 131 * 128; dst = cw1T + (size_t)l * SEG0; K = 131; O = 128; SD = 168; j = r; }
    else if ((r -= SEG0) < SEG1) { src = ew1 + (size_t)l * 131 * 128; dst = ew1T + (size_t)l * SEG1; K = 131; O = 128; SD = 168; j = r; }
    else if ((r -= SEG1) < SEG2) { src = ew2 + (size_t)l * 128 * 64; dst = ew2T + (size_t)l * SEG2; K = 128; O = 64; SD = 136; j = r; }
    else if ((r -= SEG2) < SEG3) { src = nw1 + (size_t)l * 128 * 128; dst = nw1T + (size_t)l * SEG3; K = 128; O = 128; SD = 136; j = r; }
    else if ((r -= SEG3) < SEG4) { src = nw2 + (size_t)l * 128 * 64; dst = nw2T + (size_t)l * SEG4; K = 128; O = 64; SD = 136; j = r; }
    else {
        r -= SEG4;
        const float* s2 = cw2 + (size_t)l * 128 * 3;
        int o = r / 136, k = r - o * 136;
        cw2T[(size_t)l * SEG5 + r] = (o < 3 && k < 128) ? (_Float16)s2[(size_t)k * 3 + o] : (_Float16)0.0f;
        return;
    }
    int o = j / SD, k = j - o * SD;
    dst[j] = (k < K) ? (_Float16)src[(size_t)k * O + o] : (_Float16)0.0f;
}

// ---- CSR build ----
__global__ void k_hist(const int* __restrict__ row, int* __restrict__ deg) {
    int e = blockIdx.x * blockDim.x + threadIdx.x;
    if (e < NE) atomicAdd(&deg[row[e]], 1);
}
#define SCB 256
#define SCT 256
#define SCCH ((NN + SCB - 1) / SCB)
__global__ void k_scan_part(const int* __restrict__ deg, int* __restrict__ bsum) {
    __shared__ int red[SCT];
    int b = blockIdx.x;
    int s = b * SCCH, e = min(NN, s + SCCH);
    int sum = 0;
    for (int i = s + threadIdx.x; i < e; i += SCT) sum += deg[i];
    red[threadIdx.x] = sum;
    __syncthreads();
    for (int off = SCT / 2; off > 0; off >>= 1) {
        if (threadIdx.x < off) red[threadIdx.x] += red[threadIdx.x + off];
        __syncthreads();
    }
    if (threadIdx.x == 0) bsum[b] = red[0];
}
__global__ void k_scan_mid(int* __restrict__ bsum) {
    __shared__ int ss[SCB];
    int t = threadIdx.x;
    ss[t] = bsum[t];
    __syncthreads();
    if (t == 0) {
        int run = 0;
        for (int i = 0; i < SCB; ++i) { int v = ss[i]; ss[i] = run; run += v; }
    }
    __syncthreads();
    bsum[t] = ss[t];
}
__global__ void k_scan_fin(const int* __restrict__ deg, const int* __restrict__ bsum,
                           int* __restrict__ rowptr) {
    __shared__ int tsum[SCT];
    int b = blockIdx.x;
    int s = b * SCCH, e = min(NN, s + SCCH);
    const int per = (SCCH + SCT - 1) / SCT;
    int ts = s + threadIdx.x * per;
    int te = min(e, ts + per);
    int sum = 0;
    for (int i = ts; i < te; ++i) sum += deg[i];
    tsum[threadIdx.x] = sum;
    __syncthreads();
    if (threadIdx.x == 0) {
        int run = bsum[b];
        for (int i = 0; i < SCT; ++i) { int v = tsum[i]; tsum[i] = run; run += v; }
    }
    __syncthreads();
    int run = tsum[threadIdx.x];
    for (int i = ts; i < te; ++i) { rowptr[i] = run; run += deg[i]; }
    if (b == 0 && threadIdx.x == 0) rowptr[NN] = NE;
}
__global__ void k_scatter2(const int* __restrict__ row, const int* __restrict__ col,
                           int* __restrict__ pos, int* __restrict__ rowP,
                           int* __restrict__ colP) {
    int e = blockIdx.x * blockDim.x + threadIdx.x;
    if (e < NE) {
        int r = row[e];
        int p = atomicAdd(&pos[r], 1);
        rowP[p] = r;
        colP[p] = col[e];
    }
}

// ---- coord: block-coop GEMM1 + ks-split GEMM2; gathers prefetched 1 tile ahead
template <int CSR>
__global__ __launch_bounds__(256)
void k_coord3(const _Float16* __restrict__ h16,
              const float* __restrict__ ccur, float* __restrict__ cnext,
              const int* __restrict__ rowP, const int* __restrict__ colP,
              float4* __restrict__ deltas,
              const _Float16* __restrict__ w1T, const float* __restrict__ b1,
              const _Float16* __restrict__ w2T, const float* __restrict__ b2,
              const float* __restrict__ eww, const float* __restrict__ ewb,
              const float* __restrict__ cns) {
    __shared__ __attribute__((aligned(16))) _Float16 cin[32][168];
    __shared__ __attribute__((aligned(16))) _Float16 h1[32][136];
    __shared__ __attribute__((aligned(16))) float pbuf[4][32][17];
    __shared__ float gate[32];
    for (int i = threadIdx.x; i < 32 * 168; i += 256) (&cin[0][0])[i] = (_Float16)0.0f;
    int tid = threadIdx.x;
    int w = tid >> 6, lane = tid & 63, lc = lane & 15, lg = lane >> 4;
    int el = tid >> 3, part = tid & 7;
    float e0w = eww[0], e1w = eww[1], e2w = eww[2], ebw = ewb[0], sc = cns[0];
    float b20 = b2[0], b21 = b2[1], b22 = b2[2];
    f16x8 bw1[2][5];
#pragma unroll
    for (int ti = 0; ti < 2; ++ti)
#pragma unroll
        for (int ks = 0; ks < 5; ++ks)
            bw1[ti][ks] = *(const f16x8*)&w1T[(size_t)((2 * w + ti) * 16 + lc) * 168 + ks * 32 + lg * 8];
    f16x8 bw2 = *(const f16x8*)&w2T[(size_t)lc * 136 + w * 32 + lg * 8];
    float bias10 = b1[(2 * w) * 16 + lc], bias11 = b1[(2 * w + 1) * 16 + lc];
    __syncthreads();

    const int nw = gridDim.x;
    f16x8 vr, vc;
    float crx = 0.f, cry = 0.f, crz = 0.f, ccx = 0.f, ccy = 0.f, ccz = 0.f;
    if (blockIdx.x < NT_E) {  // prefetch first tile
        int e0 = blockIdx.x * 32;
        int r = rowP[e0 + el], c = colP[e0 + el];
        vr = *(const f16x8*)&h16[(size_t)r * 64 + part * 8];
        vc = *(const f16x8*)&h16[(size_t)c * 64 + part * 8];
        if (tid < 32) {
            int rr = rowP[e0 + tid], c2 = colP[e0 + tid];
            crx = ccur[rr * 3 + 0]; cry = ccur[rr * 3 + 1]; crz = ccur[rr * 3 + 2];
            ccx = ccur[c2 * 3 + 0]; ccy = ccur[c2 * 3 + 1]; ccz = ccur[c2 * 3 + 2];
        }
    }

    for (int tile = blockIdx.x; tile < NT_E; tile += nw) {
        int e0 = tile * 32;
        *(f16x8*)&cin[el][part * 8] = vr;
        *(f16x8*)&cin[el][64 + part * 8] = vc;
        int r_cur = 0;
        if (tid < 32) {
            float rx = crx - ccx, ry = cry - ccy, rz = crz - ccz;
            cin[tid][128] = (_Float16)rx; cin[tid][129] = (_Float16)ry; cin[tid][130] = (_Float16)rz;
            gate[tid] = fsig_(fmaf(rx, e0w, fmaf(ry, e1w, fmaf(rz, e2w, ebw))));
            if (!CSR) r_cur = rowP[e0 + tid];
        }
        {   // prefetch next tile (hidden under this tile's compute)
            int nt = tile + nw;
            if (nt < NT_E) {
                int e1 = nt * 32;
                int r = rowP[e1 + el], c = colP[e1 + el];
                vr = *(const f16x8*)&h16[(size_t)r * 64 + part * 8];
                vc = *(const f16x8*)&h16[(size_t)c * 64 + part * 8];
                if (tid < 32) {
                    int rr = rowP[e1 + tid], c2 = colP[e1 + tid];
                    crx = ccur[rr * 3 + 0]; cry = ccur[rr * 3 + 1]; crz = ccur[rr * 3 + 2];
                    ccx = ccur[c2 * 3 + 0]; ccy = ccur[c2 * 3 + 1]; ccz = ccur[c2 * 3 + 2];
                }
            }
        }
        __syncthreads();
        f32x4 acc[2][2];
        acc[0][0] = acc[0][1] = acc[1][0] = acc[1][1] = (f32x4){0.f, 0.f, 0.f, 0.f};
#pragma unroll
        for (int ks = 0; ks < 5; ++ks) {
            f16x8 a0 = *(const f16x8*)&cin[lc][ks * 32 + lg * 8];
            f16x8 a1 = *(const f16x8*)&cin[16 + lc][ks * 32 + lg * 8];
#pragma unroll
            for (int ti = 0; ti < 2; ++ti) {
                acc[0][ti] = MFMA16(a0, bw1[ti][ks], acc[0][ti]);
                acc[1][ti] = MFMA16(a1, bw1[ti][ks], acc[1][ti]);
            }
        }
#pragma unroll
        for (int ti = 0; ti < 2; ++ti) {
            int colc = (2 * w + ti) * 16 + lc;
            float bias = ti ? bias11 : bias10;
#pragma unroll
            for (int rt = 0; rt < 2; ++rt)
#pragma unroll
                for (int j = 0; j < 4; ++j)
                    h1[rt * 16 + lg * 4 + j][colc] = (_Float16)fsilu_(acc[rt][ti][j] + bias);
        }
        __syncthreads();
        f32x4 c2[2];
        c2[0] = c2[1] = (f32x4){0.f, 0.f, 0.f, 0.f};
        {
            f16x8 a0 = *(const f16x8*)&h1[lc][w * 32 + lg * 8];
            f16x8 a1 = *(const f16x8*)&h1[16 + lc][w * 32 + lg * 8];
            c2[0] = MFMA16(a0, bw2, c2[0]);
            c2[1] = MFMA16(a1, bw2, c2[1]);
        }
#pragma unroll
        for (int rt = 0; rt < 2; ++rt)
#pragma unroll
            for (int j = 0; j < 4; ++j)
                pbuf[w][rt * 16 + lg * 4 + j][lc] = c2[rt][j];
        __syncthreads();
        if (tid < 32) {
            float d0 = pbuf[0][tid][0] + pbuf[1][tid][0] + pbuf[2][tid][0] + pbuf[3][tid][0] + b20;
            float d1 = pbuf[0][tid][1] + pbuf[1][tid][1] + pbuf[2][tid][1] + pbuf[3][tid][1] + b21;
            float d2 = pbuf[0][tid][2] + pbuf[1][tid][2] + pbuf[2][tid][2] + pbuf[3][tid][2] + b22;
            float ss = d0 * d0 + d1 * d1 + d2 * d2;
            float nrm = fmaxf(__builtin_amdgcn_sqrtf(ss), 1e-8f);
            float m = sc * __builtin_amdgcn_rcpf(nrm) * gate[tid];
            if (CSR) {
                deltas[e0 + tid] = make_float4(d0 * m, d1 * m, d2 * m, 0.0f);
            } else {
                atomicAdd(&cnext[(size_t)r_cur * 3 + 0], d0 * m);
                atomicAdd(&cnext[(size_t)r_cur * 3 + 1], d1 * m);
                atomicAdd(&cnext[(size_t)r_cur * 3 + 2], d2 * m);
            }
        }
    }
}

__global__ void k_coord_apply(const float* __restrict__ ccur, float* __restrict__ cnext,
                              const int* __restrict__ rowptr,
                              const float4* __restrict__ deltas) {
    int n = blockIdx.x * blockDim.x + threadIdx.x;
    if (n >= NN) return;
    int s = rowptr[n], e = rowptr[n + 1];
    float d0 = 0.f, d1 = 0.f, d2 = 0.f;
    for (int j = s; j < e; ++j) {
        float4 d = deltas[j];
        d0 += d.x; d1 += d.y; d2 += d.z;
    }
    cnext[(size_t)n * 3 + 0] = ccur[(size_t)n * 3 + 0] + d0;
    cnext[(size_t)n * 3 + 1] = ccur[(size_t)n * 3 + 1] + d1;
    cnext[(size_t)n * 3 + 2] = ccur[(size_t)n * 3 + 2] + d2;
}

// ---- edge: gathers prefetched 1 tile ahead; CSR=1 -> emsgS[slot]; CSR=0 -> atomic agg
template <int CSR>
__global__ __launch_bounds__(256)
void k_edge3(const _Float16* __restrict__ h16, const float* __restrict__ coords,
             float* __restrict__ agg, _Float16* __restrict__ emsgS,
             const int* __restrict__ rowP, const int* __restrict__ colP,
             const _Float16* __restrict__ w1T, const float* __restrict__ b1,
             const _Float16* __restrict__ w2T, const float* __restrict__ b2) {
    __shared__ __attribute__((aligned(16))) _Float16 cin[32][168];
    __shared__ __attribute__((aligned(16))) _Float16 h1[32][136];
    __shared__ __attribute__((aligned(16))) _Float16 msg[32][72];
    for (int i = threadIdx.x; i < 32 * 168; i += 256) (&cin[0][0])[i] = (_Float16)0.0f;
    int tid = threadIdx.x;
    int w = tid >> 6, lane = tid & 63, lc = lane & 15, lg = lane >> 4;
    int el = tid >> 3, part = tid & 7;
    f16x8 bw1[2][5];
#pragma unroll
    for (int ti = 0; ti < 2; ++ti)
#pragma unroll
        for (int ks = 0; ks < 5; ++ks)
            bw1[ti][ks] = *(const f16x8*)&w1T[(size_t)((2 * w + ti) * 16 + lc) * 168 + ks * 32 + lg * 8];
    f16x8 bw2[4];
#pragma unroll
    for (int ks = 0; ks < 4; ++ks)
        bw2[ks] = *(const f16x8*)&w2T[(size_t)(w * 16 + lc) * 136 + ks * 32 + lg * 8];
    float bias10 = b1[(2 * w) * 16 + lc], bias11 = b1[(2 * w + 1) * 16 + lc];
    float bias2 = b2[w * 16 + lc];
    __syncthreads();

    const int nw = gridDim.x;
    f16x8 vr, vc;
    float crx = 0.f, cry = 0.f, crz = 0.f, ccx = 0.f, ccy = 0.f, ccz = 0.f;
    if (blockIdx.x < NT_E) {
        int e0 = blockIdx.x * 32;
        int r = rowP[e0 + el], c = colP[e0 + el];
        vr = *(const f16x8*)&h16[(size_t)r * 64 + part * 8];
        vc = *(const f16x8*)&h16[(size_t)c * 64 + part * 8];
        if (tid < 32) {
            int rr = rowP[e0 + tid], c2 = colP[e0 + tid];
            crx = coords[rr * 3 + 0]; cry = coords[rr * 3 + 1]; crz = coords[rr * 3 + 2];
            ccx = coords[c2 * 3 + 0]; ccy = coords[c2 * 3 + 1]; ccz = coords[c2 * 3 + 2];
        }
    }

    for (int tile = blockIdx.x; tile < NT_E; tile += nw) {
        int e0 = tile * 32;
        *(f16x8*)&cin[el][part * 8] = vr;
        *(f16x8*)&cin[el][64 + part * 8] = vc;
        if (tid < 32) {
            cin[tid][128] = (_Float16)(crx - ccx);
            cin[tid][129] = (_Float16)(cry - ccy);
            cin[tid][130] = (_Float16)(crz - ccz);
        }
        {   // prefetch next tile
            int nt = tile + nw;
            if (nt < NT_E) {
                int e1 = nt * 32;
                int r = rowP[e1 + el], c = colP[e1 + el];
                vr = *(const f16x8*)&h16[(size_t)r * 64 + part * 8];
                vc = *(const f16x8*)&h16[(size_t)c * 64 + part * 8];
                if (tid < 32) {
                    int rr = rowP[e1 + tid], c2 = colP[e1 + tid];
                    crx = coords[rr * 3 + 0]; cry = coords[rr * 3 + 1]; crz = coords[rr * 3 + 2];
                    ccx = coords[c2 * 3 + 0]; ccy = coords[c2 * 3 + 1]; ccz = coords[c2 * 3 + 2];
                }
            }
        }
        __syncthreads();
        f32x4 acc[2][2];
        acc[0][0] = acc[0][1] = acc[1][0] = acc[1][1] = (f32x4){0.f, 0.f, 0.f, 0.f};
#pragma unroll
        for (int ks = 0; ks < 5; ++ks) {
            f16x8 a0 = *(const f16x8*)&cin[lc][ks * 32 + lg * 8];
            f16x8 a1 = *(const f16x8*)&cin[16 + lc][ks * 32 + lg * 8];
#pragma unroll
            for (int ti = 0; ti < 2; ++ti) {
                acc[0][ti] = MFMA16(a0, bw1[ti][ks], acc[0][ti]);
                acc[1][ti] = MFMA16(a1, bw1[ti][ks], acc[1][ti]);
            }
        }
#pragma unroll
        for (int ti = 0; ti < 2; ++ti) {
            int colc = (2 * w + ti) * 16 + lc;
            float bias = ti ? bias11 : bias10;
#pragma unroll
            for (int rt = 0; rt < 2; ++rt)
#pragma unroll
                for (int j = 0; j < 4; ++j)
                    h1[rt * 16 + lg * 4 + j][colc] = (_Float16)fsilu_(acc[rt][ti][j] + bias);
        }
        __syncthreads();
        f32x4 c2[2];
        c2[0] = c2[1] = (f32x4){0.f, 0.f, 0.f, 0.f};
#pragma unroll
        for (int ks = 0; ks < 4; ++ks) {
            f16x8 a0 = *(const f16x8*)&h1[lc][ks * 32 + lg * 8];
            f16x8 a1 = *(const f16x8*)&h1[16 + lc][ks * 32 + lg * 8];
            c2[0] = MFMA16(a0, bw2[ks], c2[0]);
            c2[1] = MFMA16(a1, bw2[ks], c2[1]);
        }
        if (CSR) {
#pragma unroll
            for (int rt = 0; rt < 2; ++rt)
#pragma unroll
                for (int j = 0; j < 4; ++j)
                    msg[rt * 16 + lg * 4 + j][w * 16 + lc] = (_Float16)fsilu_(c2[rt][j] + bias2);
            __syncthreads();
            int r = tid >> 3, p2 = tid & 7;
            *(f16x8*)&emsgS[(size_t)(e0 + r) * 64 + p2 * 8] = *(const f16x8*)&msg[r][p2 * 8];
        } else {
#pragma unroll
            for (int rt = 0; rt < 2; ++rt)
#pragma unroll
                for (int j = 0; j < 4; ++j)
                    atomicAdd(&agg[(size_t)rowP[e0 + rt * 16 + lg * 4 + j] * 64 + w * 16 + lc],
                              fsilu_(c2[rt][j] + bias2));
            __syncthreads();
        }
    }
}

// ---- node: CSR=1 -> contiguous emsgS range per node; else agg read
template <int CSR>
__global__ __launch_bounds__(256)
void k_node3(float* __restrict__ h32, _Float16* __restrict__ h16,
             const float* __restrict__ agg, const _Float16* __restrict__ emsgS,
             const int* __restrict__ rowptr,
             const _Float16* __restrict__ w1T, const float* __restrict__ b1,
             const _Float16* __restrict__ w2T, const float* __restrict__ b2) {
    __shared__ __attribute__((aligned(16))) _Float16 cin[32][136];
    __shared__ __attribute__((aligned(16))) _Float16 h1[32][136];
    __shared__ __attribute__((aligned(16))) float vbuf[32][64];
    int tid = threadIdx.x;
    int w = tid >> 6, lane = tid & 63, lc = lane & 15, lg = lane >> 4;
    f16x8 bw1[2][4], bw2[4];
#pragma unroll
    for (int ti = 0; ti < 2; ++ti)
#pragma unroll
        for (int ks = 0; ks < 4; ++ks)
            bw1[ti][ks] = *(const f16x8*)&w1T[(size_t)((2 * w + ti) * 16 + lc) * 136 + ks * 32 + lg * 8];
#pragma unroll
    for (int ks = 0; ks < 4; ++ks)
        bw2[ks] = *(const f16x8*)&w2T[(size_t)(w * 16 + lc) * 136 + ks * 32 + lg * 8];
    float bias10 = b1[(2 * w) * 16 + lc], bias11 = b1[(2 * w + 1) * 16 + lc];
    float bias2 = b2[w * 16 + lc];

    for (int tile = blockIdx.x; tile < NT_N; tile += gridDim.x) {
        int n0 = tile * 32;
        {
            int nl = tid >> 3, part = tid & 7;
            int n = n0 + nl;
            *(f16x8*)&cin[nl][part * 8] = *(const f16x8*)&h16[(size_t)n * 64 + part * 8];
            if (CSR) {
                float a[8] = {0.f, 0.f, 0.f, 0.f, 0.f, 0.f, 0.f, 0.f};
                int s = rowptr[n], e = rowptr[n + 1];
                for (int jj = s; jj < e; ++jj) {
                    f16x8 m = *(const f16x8*)&emsgS[(size_t)jj * 64 + part * 8];
#pragma unroll
                    for (int q = 0; q < 8; ++q) a[q] += (float)m[q];
                }
                f16x8 o;
#pragma unroll
                for (int q = 0; q < 8; ++q) o[q] = (_Float16)a[q];
                *(f16x8*)&cin[nl][64 + part * 8] = o;
            } else {
                f32x4 xx = *(const f32x4*)&agg[(size_t)n * 64 + part * 8];
                f32x4 yy = *(const f32x4*)&agg[(size_t)n * 64 + part * 8 + 4];
                f16x8 o;
                o[0] = (_Float16)xx[0]; o[1] = (_Float16)xx[1]; o[2] = (_Float16)xx[2]; o[3] = (_Float16)xx[3];
                o[4] = (_Float16)yy[0]; o[5] = (_Float16)yy[1]; o[6] = (_Float16)yy[2]; o[7] = (_Float16)yy[3];
                *(f16x8*)&cin[nl][64 + part * 8] = o;
            }
        }
        __syncthreads();
        f32x4 acc[2][2];
        acc[0][0] = acc[0][1] = acc[1][0] = acc[1][1] = (f32x4){0.f, 0.f, 0.f, 0.f};
#pragma unroll
        for (int ks = 0; ks < 4; ++ks) {
            f16x8 a0 = *(const f16x8*)&cin[lc][ks * 32 + lg * 8];
            f16x8 a1 = *(const f16x8*)&cin[16 + lc][ks * 32 + lg * 8];
#pragma unroll
            for (int ti = 0; ti < 2; ++ti) {
                acc[0][ti] = MFMA16(a0, bw1[ti][ks], acc[0][ti]);
                acc[1][ti] = MFMA16(a1, bw1[ti][ks], acc[1][ti]);
            }
        }
#pragma unroll
        for (int ti = 0; ti < 2; ++ti) {
            int colc = (2 * w + ti) * 16 + lc;
            float bias = ti ? bias11 : bias10;
#pragma unroll
            for (int rt = 0; rt < 2; ++rt)
#pragma unroll
                for (int j = 0; j < 4; ++j)
                    h1[rt * 16 + lg * 4 + j][colc] = (_Float16)fsilu_(acc[rt][ti][j] + bias);
        }
        __syncthreads();
        f32x4 c2[2];
        c2[0] = c2[1] = (f32x4){0.f, 0.f, 0.f, 0.f};
#pragma unroll
        for (int ks = 0; ks < 4; ++ks) {
            f16x8 a0 = *(const f16x8*)&h1[lc][ks * 32 + lg * 8];
            f16x8 a1 = *(const f16x8*)&h1[16 + lc][ks * 32 + lg * 8];
            c2[0] = MFMA16(a0, bw2[ks], c2[0]);
            c2[1] = MFMA16(a1, bw2[ks], c2[1]);
        }
#pragma unroll
        for (int rt = 0; rt < 2; ++rt)
#pragma unroll
            for (int j = 0; j < 4; ++j) {
                int rl = rt * 16 + lg * 4 + j, colc = w * 16 + lc;
                vbuf[rl][colc] = h32[(size_t)(n0 + rl) * 64 + colc] + c2[rt][j] + bias2;
            }
        __syncthreads();
        {
            int r = w * 8 + (lane >> 3), sub = lane & 7;
            f32x4 v0 = *(const f32x4*)&vbuf[r][sub * 8];
            f32x4 v1 = *(const f32x4*)&vbuf[r][sub * 8 + 4];
            float s = v0[0] + v0[1] + v0[2] + v0[3] + v1[0] + v1[1] + v1[2] + v1[3];
            float sq = v0[0]*v0[0] + v0[1]*v0[1] + v0[2]*v0[2] + v0[3]*v0[3]
                     + v1[0]*v1[0] + v1[1]*v1[1] + v1[2]*v1[2] + v1[3]*v1[3];
            s += __shfl_xor(s, 1); s += __shfl_xor(s, 2); s += __shfl_xor(s, 4);
            sq += __shfl_xor(sq, 1); sq += __shfl_xor(sq, 2); sq += __shfl_xor(sq, 4);
            float mu = s * (1.0f / 64.0f);
            float var = sq * (1.0f / 64.0f) - mu * mu;
            float rs = __builtin_amdgcn_rcpf(__builtin_amdgcn_sqrtf(var + 1e-5f));
            size_t base = (size_t)(n0 + r) * 64 + sub * 8;
            f32x4 o0, o1; f16x8 oh;
#pragma unroll
            for (int i = 0; i < 4; ++i) {
                o0[i] = (v0[i] - mu) * rs;
                o1[i] = (v1[i] - mu) * rs;
                oh[i] = (_Float16)o0[i];
                oh[4 + i] = (_Float16)o1[i];
            }
            *(f32x4*)&h32[base] = o0;
            *(f32x4*)&h32[base + 4] = o1;
            *(f16x8*)&h16[base] = oh;
        }
        __syncthreads();
    }
}

__global__ void k_pool_seg(const float* __restrict__ h, const int* __restrict__ batch,
                           float* __restrict__ pooled, float* __restrict__ cnt) {
    int lane = threadIdx.x & 63;
    int wid = blockIdx.x * (blockDim.x >> 6) + (threadIdx.x >> 6);
    int nwav = gridDim.x * (blockDim.x >> 6);
    int chunk = (NN + nwav - 1) / nwav;
    int s = wid * chunk;
    if (s >= NN) return;
    int e = s + chunk; if (e > NN) e = NN;
    int g = batch[s];
    float acc = 0.0f, c = 0.0f;
    for (int n = s; n < e; ++n) {
        int b = batch[n];
        if (b != g) {
            atomicAdd(&pooled[g * 64 + lane], acc);
            if (lane == 0) atomicAdd(&cnt[g], c);
            acc = 0.0f; c = 0.0f; g = b;
        }
        acc += h[(size_t)n * 64 + lane];
        c += 1.0f;
    }
    atomicAdd(&pooled[g * 64 + lane], acc);
    if (lane == 0) atomicAdd(&cnt[g], c);
}

__global__ void k_final(const float* __restrict__ pooled, const float* __restrict__ cnt,
                        const float* __restrict__ ow, const float* __restrict__ ob,
                        float* __restrict__ out) {
    __shared__ float red[2];
    int g = blockIdx.x, o = threadIdx.x;
    float c = fmaxf(cnt[g], 1.0f);
    float acc = ob[o];
#pragma unroll
    for (int j = 0; j < 64; ++j) {
        float pm = fmaxf(pooled[g * 64 + j] / c, 0.0f);
        acc = fmaf(pm, ow[j * 128 + o], acc);
    }
    float ss = acc * acc;
#pragma unroll
    for (int off = 32; off > 0; off >>= 1) ss += __shfl_xor(ss, off);
    if ((o & 63) == 0) red[o >> 6] = ss;
    __syncthreads();
    float nrm = sqrtf(red[0] + red[1]);
    out[g * 128 + o] = acc / fmaxf(nrm, 1e-12f);
}

extern "C" void kernel_launch(void* const* d_in, const int* in_sizes, int n_in,
                              void* d_out, int out_size, void* d_ws, size_t ws_size,
                              hipStream_t stream) {
    const float* x         = (const float*)d_in[0];
    const float* coords_in = (const float*)d_in[1];
    const float* in_w      = (const float*)d_in[2];
    const float* in_b      = (const float*)d_in[3];
    const float* coord_w1  = (const float*)d_in[4];
    const float* coord_b1  = (const float*)d_in[5];
    const float* coord_w2  = (const float*)d_in[6];
    const float* coord_b2  = (const float*)d_in[7];
    const float* ew_w      = (const float*)d_in[8];
    const float* ew_b      = (const float*)d_in[9];
    const float* cn_scale  = (const float*)d_in[10];
    const float* edge_w1   = (const float*)d_in[11];
    const float* edge_b1   = (const float*)d_in[12];
    const float* edge_w2   = (const float*)d_in[13];
    const float* edge_b2   = (const float*)d_in[14];
    const float* node_w1   = (const float*)d_in[15];
    const float* node_b1   = (const float*)d_in[16];
    const float* node_w2   = (const float*)d_in[17];
    const float* node_b2   = (const float*)d_in[18];
    const float* out_w     = (const float*)d_in[19];
    const float* out_b     = (const float*)d_in[20];
    const int* ei          = (const int*)d_in[21];
    const int* batch       = (const int*)d_in[22];
    const int* row = ei;
    const int* col = ei + NE;

    char* wp = (char*)d_ws;
    float* h32    = (float*)wp; wp += (size_t)NN * 64 * 4;
    float* cA     = (float*)wp; wp += (size_t)NN * 3 * 4;
    float* cB     = (float*)wp; wp += (size_t)NN * 3 * 4;
    float* pooled = (float*)wp; wp += (size_t)NG * 64 * 4;
    float* cnt    = (float*)wp; wp += (size_t)NG * 4;
    _Float16* h16  = (_Float16*)wp; wp += (size_t)NN * 64 * 2;
    _Float16* cw1T = (_Float16*)wp; wp += (size_t)NL * SEG0 * 2;
    _Float16* ew1T = (_Float16*)wp; wp += (size_t)NL * SEG1 * 2;
    _Float16* ew2T = (_Float16*)wp; wp += (size_t)NL * SEG2 * 2;
    _Float16* nw1T = (_Float16*)wp; wp += (size_t)NL * SEG3 * 2;
    _Float16* nw2T = (_Float16*)wp; wp += (size_t)NL * SEG4 * 2;
    _Float16* cw2T = (_Float16*)wp; wp += (size_t)NL * SEG5 * 2;
    // CSR region
    int* deg       = (int*)wp;            wp += (size_t)NN * 4;
    int* rowptr    = (int*)wp;            wp += (size_t)(NN + 4) * 4;
    int* pos       = (int*)wp;            wp += (size_t)NN * 4;
    int* bsum      = (int*)wp;            wp += (size_t)SCB * 4;
    int* rowP      = (int*)wp;            wp += (size_t)NE * 4;
    int* colP      = (int*)wp;            wp += (size_t)NE * 4;
    float4* deltas = (float4*)wp;         wp += (size_t)NE * 16;
    _Float16* emsgS= (_Float16*)wp;       wp += (size_t)NE * 64 * 2;
    size_t csr_need = (size_t)(wp - (char*)d_ws);
    float* agg = (float*)deg;  // legacy path union
    bool use_csr = (ws_size >= csr_need);

    if (use_csr) {
        hipMemsetAsync(deg, 0, (size_t)NN * 4, stream);
        k_hist<<<(NE + 255) / 256, 256, 0, stream>>>(row, deg);
        k_scan_part<<<SCB, SCT, 0, stream>>>(deg, bsum);
        k_scan_mid<<<1, SCB, 0, stream>>>(bsum);
        k_scan_fin<<<SCB, SCT, 0, stream>>>(deg, bsum, rowptr);
        hipMemcpyAsync(pos, rowptr, (size_t)NN * 4, hipMemcpyDeviceToDevice, stream);
        k_scatter2<<<(NE + 255) / 256, 256, 0, stream>>>(row, col, pos, rowP, colP);
    }
    k_prep_all<<<(NL * SEGTOT + 255) / 256, 256, 0, stream>>>(
        coord_w1, edge_w1, edge_w2, node_w1, node_w2, coord_w2,
        cw1T, ew1T, ew2T, nw1T, nw2T, cw2T);
    k_init_h<<<(NN * 64 + 255) / 256, 256, 0, stream>>>(x, in_w, in_b, h32, h16);

    const float* cur = coords_in;
    float* nxt = cA;
    for (int l = 0; l < NL; ++l) {
        if (use_csr) {
            k_coord3<1><<<2048, 256, 0, stream>>>(h16, cur, nullptr, rowP, colP, deltas,
                cw1T + (size_t)l * SEG0, coord_b1 + l * 128,
                cw2T + (size_t)l * SEG5, coord_b2 + l * 3,
                ew_w + l * 3, ew_b + l, cn_scale + l);
            k_coord_apply<<<(NN + 255) / 256, 256, 0, stream>>>(cur, nxt, rowptr, deltas);
            k_edge3<1><<<2048, 256, 0, stream>>>(h16, nxt, nullptr, emsgS, rowP, colP,
                ew1T + (size_t)l * SEG1, edge_b1 + l * 128,
                ew2T + (size_t)l * SEG2, edge_b2 + l * 64);
            k_node3<1><<<1024, 256, 0, stream>>>(h32, h16, nullptr, emsgS, rowptr,
                nw1T + (size_t)l * SEG3, node_b1 + l * 128,
                nw2T + (size_t)l * SEG4, node_b2 + l * 64);
        } else {
            hipMemcpyAsync(nxt, cur, (size_t)NN * 3 * sizeof(float), hipMemcpyDeviceToDevice, stream);
            k_coord3<0><<<2048, 256, 0, stream>>>(h16, cur, nxt, row, col, nullptr,
                cw1T + (size_t)l * SEG0, coord_b1 + l * 128,
                cw2T + (size_t)l * SEG5, coord_b2 + l * 3,
                ew_w + l * 3, ew_b + l, cn_scale + l);
            hipMemsetAsync(agg, 0, (size_t)NN * 64 * 4, stream);
            k_edge3<0><<<2048, 256, 0, stream>>>(h16, nxt, agg, nullptr, row, col,
                ew1T + (size_t)l * SEG1, edge_b1 + l * 128,
                ew2T + (size_t)l * SEG2, edge_b2 + l * 64);
            k_node3<0><<<1024, 256, 0, stream>>>(h32, h16, agg, nullptr, nullptr,
                nw1T + (size_t)l * SEG3, node_b1 + l * 128,
                nw2T + (size_t)l * SEG4, node_b2 + l * 64);
        }
        cur = nxt;
        nxt = (nxt == cA) ? cB : cA;
    }
    hipMemsetAsync(pooled, 0, (size_t)(NG * 64 + NG) * sizeof(float), stream);
    k_pool_seg<<<512, 256, 0, stream>>>(h32, batch, pooled, cnt);
    k_final<<<NG, 128, 0, stream>>>(pooled, cnt, out_w, out_b, (float*)d_out);
}

// Round 11
// 1162.437 us; speedup vs baseline: 1.2567x; 1.0341x over previous
//
#include <hip/hip_runtime.h>
#include <math.h>

#define NN 100000
#define NE 1000000
#define NG 64
#define NL 4
#define NT_E (NE / 32)
#define NT_N (NN / 32)

typedef __attribute__((ext_vector_type(8))) _Float16 f16x8;
typedef __attribute__((ext_vector_type(2))) _Float16 f16x2;
typedef __attribute__((ext_vector_type(4))) float f32x4;

#define MFMA16(a, b, c) __builtin_amdgcn_mfma_f32_16x16x32_f16(a, b, c, 0, 0, 0)
#define LOG2E 1.44269504088896340f
__device__ __forceinline__ float fsig_(float x) {
    return __builtin_amdgcn_rcpf(1.0f + __builtin_amdgcn_exp2f(-LOG2E * x));
}
__device__ __forceinline__ float fsilu_(float x) { return x * fsig_(x); }

__global__ void k_init_h(const float* __restrict__ x, const float* __restrict__ in_w,
                         const float* __restrict__ in_b, float* __restrict__ h32,
                         _Float16* __restrict__ h16) {
    int idx = blockIdx.x * blockDim.x + threadIdx.x;
    if (idx >= NN * 64) return;
    int n = idx >> 6, j = idx & 63;
    float v = fmaf(x[n], in_w[j], in_b[j]);
    h32[idx] = v;
    h16[idx] = (_Float16)v;
}

// transpose + fp16 + zero-pad all weight families x 4 layers.
// GEMM1 families (cw1T/ew1T/nw1T) use PERMUTED storage rows: storage row
// s = t*16+lc holds logical output col L = 32*(s>>5) + 2*(s&15) + ((s>>4)&1),
// so each wave's two fragments cover ADJACENT logical cols (f16x2 writeback).
#define SEG0 21504  // 128*168 cw1T
#define SEG1 21504  // ew1T
#define SEG2 8704   // 64*136  ew2T
#define SEG3 17408  // 128*136 nw1T
#define SEG4 8704   // nw2T
#define SEG5 2176   // 16*136  cw2T (O=3 padded to 16)
#define SEGTOT (SEG0 + SEG1 + SEG2 + SEG3 + SEG4 + SEG5)
__global__ void k_prep_all(const float* __restrict__ cw1, const float* __restrict__ ew1,
                           const float* __restrict__ ew2, const float* __restrict__ nw1,
                           const float* __restrict__ nw2, const float* __restrict__ cw2,
                           _Float16* __restrict__ cw1T, _Float16* __restrict__ ew1T,
                           _Float16* __restrict__ ew2T, _Float16* __restrict__ nw1T,
                           _Float16* __restrict__ nw2T, _Float16* __restrict__ cw2T) {
    int i = blockIdx.x * blockDim.x + threadIdx.x;
    if (i >= NL * SEGTOT) return;
    int l = i / SEGTOT, r = i - l * SEGTOT;
    const float* src; _Float16* dst; int K, O, SD, j, perm;
    if (r < SEG0) { src = cw1 + (size_t)l * 131 * 128; dst = cw1T + (size_t)l * SEG0; K = 131; O = 128; SD = 168; j = r; perm = 1; }
    else if ((r -= SEG0) < SEG1) { src = ew1 + (size_t)l * 131 * 128; dst = ew1T + (size_t)l * SEG1; K = 131; O = 128; SD = 168; j = r; perm = 1; }
    else if ((r -= SEG1) < SEG2) { src = ew2 + (size_t)l * 128 * 64; dst = ew2T + (size_t)l * SEG2; K = 128; O = 64; SD = 136; j = r; perm = 0; }
    else if ((r -= SEG2) < SEG3) { src = nw1 + (size_t)l * 128 * 128; dst = nw1T + (size_t)l * SEG3; K = 128; O = 128; SD = 136; j = r; perm = 1; }
    else if ((r -= SEG3) < SEG4) { src = nw2 + (size_t)l * 128 * 64; dst = nw2T + (size_t)l * SEG4; K = 128; O = 64; SD = 136; j = r; perm = 0; }
    else {
        r -= SEG4;
        const float* s2 = cw2 + (size_t)l * 128 * 3;
        int o = r / 136, k = r - o * 136;
        cw2T[(size_t)l * SEG5 + r] = (o < 3 && k < 128) ? (_Float16)s2[(size_t)k * 3 + o] : (_Float16)0.0f;
        return;
    }
    int o = j / SD, k = j - o * SD;
    int L = perm ? (32 * (o >> 5) + 2 * (o & 15) + ((o >> 4) & 1)) : o;
    dst[j] = (k < K) ? (_Float16)src[(size_t)k * O + L] : (_Float16)0.0f;
}

// ---- CSR build ----
__global__ void k_hist(const int* __restrict__ row, int* __restrict__ deg) {
    int e = blockIdx.x * blockDim.x + threadIdx.x;
    if (e < NE) atomicAdd(&deg[row[e]], 1);
}
#define SCB 256
#define SCT 256
#define SCCH ((NN + SCB - 1) / SCB)
__global__ void k_scan_part(const int* __restrict__ deg, int* __restrict__ bsum) {
    __shared__ int red[SCT];
    int b = blockIdx.x;
    int s = b * SCCH, e = min(NN, s + SCCH);
    int sum = 0;
    for (int i = s + threadIdx.x; i < e; i += SCT) sum += deg[i];
    red[threadIdx.x] = sum;
    __syncthreads();
    for (int off = SCT / 2; off > 0; off >>= 1) {
        if (threadIdx.x < off) red[threadIdx.x] += red[threadIdx.x + off];
        __syncthreads();
    }
    if (threadIdx.x == 0) bsum[b] = red[0];
}
__global__ void k_scan_mid(int* __restrict__ bsum) {
    __shared__ int ss[SCB];
    int t = threadIdx.x;
    ss[t] = bsum[t];
    __syncthreads();
    if (t == 0) {
        int run = 0;
        for (int i = 0; i < SCB; ++i) { int v = ss[i]; ss[i] = run; run += v; }
    }
    __syncthreads();
    bsum[t] = ss[t];
}
__global__ void k_scan_fin(const int* __restrict__ deg, const int* __restrict__ bsum,
                           int* __restrict__ rowptr) {
    __shared__ int tsum[SCT];
    int b = blockIdx.x;
    int s = b * SCCH, e = min(NN, s + SCCH);
    const int per = (SCCH + SCT - 1) / SCT;
    int ts = s + threadIdx.x * per;
    int te = min(e, ts + per);
    int sum = 0;
    for (int i = ts; i < te; ++i) sum += deg[i];
    tsum[threadIdx.x] = sum;
    __syncthreads();
    if (threadIdx.x == 0) {
        int run = bsum[b];
        for (int i = 0; i < SCT; ++i) { int v = tsum[i]; tsum[i] = run; run += v; }
    }
    __syncthreads();
    int run = tsum[threadIdx.x];
    for (int i = ts; i < te; ++i) { rowptr[i] = run; run += deg[i]; }
    if (b == 0 && threadIdx.x == 0) rowptr[NN] = NE;
}
__global__ void k_scatter2(const int* __restrict__ row, const int* __restrict__ col,
                           int* __restrict__ pos, int* __restrict__ rowP,
                           int* __restrict__ colP) {
    int e = blockIdx.x * blockDim.x + threadIdx.x;
    if (e < NE) {
        int r = row[e];
        int p = atomicAdd(&pos[r], 1);
        rowP[p] = r;
        colP[p] = col[e];
    }
}

// ---- coord: block-coop GEMM1 (paired cols) + ks-split GEMM2 ----
template <int CSR>
__global__ __launch_bounds__(256)
void k_coord3(const _Float16* __restrict__ h16,
              const float* __restrict__ ccur, float* __restrict__ cnext,
              const int* __restrict__ rowP, const int* __restrict__ colP,
              float4* __restrict__ deltas,
              const _Float16* __restrict__ w1T, const float* __restrict__ b1,
              const _Float16* __restrict__ w2T, const float* __restrict__ b2,
              const float* __restrict__ eww, const float* __restrict__ ewb,
              const float* __restrict__ cns) {
    __shared__ __attribute__((aligned(16))) _Float16 cin[32][168];
    __shared__ __attribute__((aligned(16))) _Float16 h1[32][136];
    __shared__ __attribute__((aligned(16))) float pbuf[4][32][17];
    __shared__ float gate[32];
    for (int i = threadIdx.x; i < 32 * 168; i += 256) (&cin[0][0])[i] = (_Float16)0.0f;
    int tid = threadIdx.x;
    int w = tid >> 6, lane = tid & 63, lc = lane & 15, lg = lane >> 4;
    float e0w = eww[0], e1w = eww[1], e2w = eww[2], ebw = ewb[0], sc = cns[0];
    float b20 = b2[0], b21 = b2[1], b22 = b2[2];
    f16x8 bw1[2][5];
#pragma unroll
    for (int ti = 0; ti < 2; ++ti)
#pragma unroll
        for (int ks = 0; ks < 5; ++ks)
            bw1[ti][ks] = *(const f16x8*)&w1T[(size_t)((2 * w + ti) * 16 + lc) * 168 + ks * 32 + lg * 8];
    f16x8 bw2 = *(const f16x8*)&w2T[(size_t)lc * 136 + w * 32 + lg * 8];
    float bias10 = b1[32 * w + 2 * lc], bias11 = b1[32 * w + 2 * lc + 1];
    __syncthreads();

    for (int tile = blockIdx.x; tile < NT_E; tile += gridDim.x) {
        int e0 = tile * 32;
        {
            int el = tid >> 3, part = tid & 7;
            int r = rowP[e0 + el], c = colP[e0 + el];
            *(f16x8*)&cin[el][part * 8] = *(const f16x8*)&h16[(size_t)r * 64 + part * 8];
            *(f16x8*)&cin[el][64 + part * 8] = *(const f16x8*)&h16[(size_t)c * 64 + part * 8];
        }
        if (tid < 32) {
            int r = rowP[e0 + tid], c = colP[e0 + tid];
            float rx = ccur[r * 3 + 0] - ccur[c * 3 + 0];
            float ry = ccur[r * 3 + 1] - ccur[c * 3 + 1];
            float rz = ccur[r * 3 + 2] - ccur[c * 3 + 2];
            cin[tid][128] = (_Float16)rx; cin[tid][129] = (_Float16)ry; cin[tid][130] = (_Float16)rz;
            gate[tid] = fsig_(fmaf(rx, e0w, fmaf(ry, e1w, fmaf(rz, e2w, ebw))));
        }
        __syncthreads();
        f32x4 acc[2][2];
        acc[0][0] = acc[0][1] = acc[1][0] = acc[1][1] = (f32x4){0.f, 0.f, 0.f, 0.f};
#pragma unroll
        for (int ks = 0; ks < 5; ++ks) {
            f16x8 a0 = *(const f16x8*)&cin[lc][ks * 32 + lg * 8];
            f16x8 a1 = *(const f16x8*)&cin[16 + lc][ks * 32 + lg * 8];
#pragma unroll
            for (int ti = 0; ti < 2; ++ti) {
                acc[0][ti] = MFMA16(a0, bw1[ti][ks], acc[0][ti]);
                acc[1][ti] = MFMA16(a1, bw1[ti][ks], acc[1][ti]);
            }
        }
#pragma unroll
        for (int rt = 0; rt < 2; ++rt)
#pragma unroll
            for (int j = 0; j < 4; ++j) {
                f16x2 p;
                p[0] = (_Float16)fsilu_(acc[rt][0][j] + bias10);
                p[1] = (_Float16)fsilu_(acc[rt][1][j] + bias11);
                *(f16x2*)&h1[rt * 16 + lg * 4 + j][32 * w + 2 * lc] = p;
            }
        __syncthreads();
        f32x4 c2[2];
        c2[0] = c2[1] = (f32x4){0.f, 0.f, 0.f, 0.f};
        {
            f16x8 a0 = *(const f16x8*)&h1[lc][w * 32 + lg * 8];
            f16x8 a1 = *(const f16x8*)&h1[16 + lc][w * 32 + lg * 8];
            c2[0] = MFMA16(a0, bw2, c2[0]);
            c2[1] = MFMA16(a1, bw2, c2[1]);
        }
#pragma unroll
        for (int rt = 0; rt < 2; ++rt)
#pragma unroll
            for (int j = 0; j < 4; ++j)
                pbuf[w][rt * 16 + lg * 4 + j][lc] = c2[rt][j];
        __syncthreads();
        if (tid < 32) {
            float d0 = pbuf[0][tid][0] + pbuf[1][tid][0] + pbuf[2][tid][0] + pbuf[3][tid][0] + b20;
            float d1 = pbuf[0][tid][1] + pbuf[1][tid][1] + pbuf[2][tid][1] + pbuf[3][tid][1] + b21;
            float d2 = pbuf[0][tid][2] + pbuf[1][tid][2] + pbuf[2][tid][2] + pbuf[3][tid][2] + b22;
            float ss = d0 * d0 + d1 * d1 + d2 * d2;
            float nrm = fmaxf(__builtin_amdgcn_sqrtf(ss), 1e-8f);
            float m = sc * __builtin_amdgcn_rcpf(nrm) * gate[tid];
            if (CSR) {
                deltas[e0 + tid] = make_float4(d0 * m, d1 * m, d2 * m, 0.0f);
            } else {
                int r = rowP[e0 + tid];
                atomicAdd(&cnext[(size_t)r * 3 + 0], d0 * m);
                atomicAdd(&cnext[(size_t)r * 3 + 1], d1 * m);
                atomicAdd(&cnext[(size_t)r * 3 + 2], d2 * m);
            }
        }
    }
}

__global__ void k_coord_apply(const float* __restrict__ ccur, float* __restrict__ cnext,
                              const int* __restrict__ rowptr,
                              const float4* __restrict__ deltas) {
    int n = blockIdx.x * blockDim.x + threadIdx.x;
    if (n >= NN) return;
    int s = rowptr[n], e = rowptr[n + 1];
    float d0 = 0.f, d1 = 0.f, d2 = 0.f;
    for (int j = s; j < e; ++j) {
        float4 d = deltas[j];
        d0 += d.x; d1 += d.y; d2 += d.z;
    }
    cnext[(size_t)n * 3 + 0] = ccur[(size_t)n * 3 + 0] + d0;
    cnext[(size_t)n * 3 + 1] = ccur[(size_t)n * 3 + 1] + d1;
    cnext[(size_t)n * 3 + 2] = ccur[(size_t)n * 3 + 2] + d2;
}

// ---- edge: paired-col GEMM1; GEMM2 writes emsgS DIRECTLY (no msg LDS, 2 barriers/tile)
template <int CSR>
__global__ __launch_bounds__(256)
void k_edge3(const _Float16* __restrict__ h16, const float* __restrict__ coords,
             float* __restrict__ agg, _Float16* __restrict__ emsgS,
             const int* __restrict__ rowP, const int* __restrict__ colP,
             const _Float16* __restrict__ w1T, const float* __restrict__ b1,
             const _Float16* __restrict__ w2T, const float* __restrict__ b2) {
    __shared__ __attribute__((aligned(16))) _Float16 cin[32][168];
    __shared__ __attribute__((aligned(16))) _Float16 h1[32][136];
    for (int i = threadIdx.x; i < 32 * 168; i += 256) (&cin[0][0])[i] = (_Float16)0.0f;
    int tid = threadIdx.x;
    int w = tid >> 6, lane = tid & 63, lc = lane & 15, lg = lane >> 4;
    f16x8 bw1[2][5];
#pragma unroll
    for (int ti = 0; ti < 2; ++ti)
#pragma unroll
        for (int ks = 0; ks < 5; ++ks)
            bw1[ti][ks] = *(const f16x8*)&w1T[(size_t)((2 * w + ti) * 16 + lc) * 168 + ks * 32 + lg * 8];
    f16x8 bw2[4];
#pragma unroll
    for (int ks = 0; ks < 4; ++ks)
        bw2[ks] = *(const f16x8*)&w2T[(size_t)(w * 16 + lc) * 136 + ks * 32 + lg * 8];
    float bias10 = b1[32 * w + 2 * lc], bias11 = b1[32 * w + 2 * lc + 1];
    float bias2 = b2[w * 16 + lc];
    __syncthreads();

    for (int tile = blockIdx.x; tile < NT_E; tile += gridDim.x) {
        int e0 = tile * 32;
        {
            int el = tid >> 3, part = tid & 7;
            int r = rowP[e0 + el], c = colP[e0 + el];
            *(f16x8*)&cin[el][part * 8] = *(const f16x8*)&h16[(size_t)r * 64 + part * 8];
            *(f16x8*)&cin[el][64 + part * 8] = *(const f16x8*)&h16[(size_t)c * 64 + part * 8];
        }
        if (tid < 32) {
            int r = rowP[e0 + tid], c = colP[e0 + tid];
            cin[tid][128] = (_Float16)(coords[r * 3 + 0] - coords[c * 3 + 0]);
            cin[tid][129] = (_Float16)(coords[r * 3 + 1] - coords[c * 3 + 1]);
            cin[tid][130] = (_Float16)(coords[r * 3 + 2] - coords[c * 3 + 2]);
        }
        __syncthreads();
        f32x4 acc[2][2];
        acc[0][0] = acc[0][1] = acc[1][0] = acc[1][1] = (f32x4){0.f, 0.f, 0.f, 0.f};
#pragma unroll
        for (int ks = 0; ks < 5; ++ks) {
            f16x8 a0 = *(const f16x8*)&cin[lc][ks * 32 + lg * 8];
            f16x8 a1 = *(const f16x8*)&cin[16 + lc][ks * 32 + lg * 8];
#pragma unroll
            for (int ti = 0; ti < 2; ++ti) {
                acc[0][ti] = MFMA16(a0, bw1[ti][ks], acc[0][ti]);
                acc[1][ti] = MFMA16(a1, bw1[ti][ks], acc[1][ti]);
            }
        }
#pragma unroll
        for (int rt = 0; rt < 2; ++rt)
#pragma unroll
            for (int j = 0; j < 4; ++j) {
                f16x2 p;
                p[0] = (_Float16)fsilu_(acc[rt][0][j] + bias10);
                p[1] = (_Float16)fsilu_(acc[rt][1][j] + bias11);
                *(f16x2*)&h1[rt * 16 + lg * 4 + j][32 * w + 2 * lc] = p;
            }
        __syncthreads();
        f32x4 c2[2];
        c2[0] = c2[1] = (f32x4){0.f, 0.f, 0.f, 0.f};
#pragma unroll
        for (int ks = 0; ks < 4; ++ks) {
            f16x8 a0 = *(const f16x8*)&h1[lc][ks * 32 + lg * 8];
            f16x8 a1 = *(const f16x8*)&h1[16 + lc][ks * 32 + lg * 8];
            c2[0] = MFMA16(a0, bw2[ks], c2[0]);
            c2[1] = MFMA16(a1, bw2[ks], c2[1]);
        }
        if (CSR) {
#pragma unroll
            for (int rt = 0; rt < 2; ++rt)
#pragma unroll
                for (int j = 0; j < 4; ++j)
                    emsgS[(size_t)(e0 + rt * 16 + lg * 4 + j) * 64 + w * 16 + lc] =
                        (_Float16)fsilu_(c2[rt][j] + bias2);
        } else {
#pragma unroll
            for (int rt = 0; rt < 2; ++rt)
#pragma unroll
                for (int j = 0; j < 4; ++j)
                    atomicAdd(&agg[(size_t)rowP[e0 + rt * 16 + lg * 4 + j] * 64 + w * 16 + lc],
                              fsilu_(c2[rt][j] + bias2));
        }
    }
}

// ---- node: paired-col GEMM1; CSR gather; 3 barriers/tile (trailing one removed)
template <int CSR>
__global__ __launch_bounds__(256)
void k_node3(float* __restrict__ h32, _Float16* __restrict__ h16,
             const float* __restrict__ agg, const _Float16* __restrict__ emsgS,
             const int* __restrict__ rowptr,
             const _Float16* __restrict__ w1T, const float* __restrict__ b1,
             const _Float16* __restrict__ w2T, const float* __restrict__ b2) {
    __shared__ __attribute__((aligned(16))) _Float16 cin[32][136];
    __shared__ __attribute__((aligned(16))) _Float16 h1[32][136];
    __shared__ __attribute__((aligned(16))) float vbuf[32][64];
    int tid = threadIdx.x;
    int w = tid >> 6, lane = tid & 63, lc = lane & 15, lg = lane >> 4;
    f16x8 bw1[2][4], bw2[4];
#pragma unroll
    for (int ti = 0; ti < 2; ++ti)
#pragma unroll
        for (int ks = 0; ks < 4; ++ks)
            bw1[ti][ks] = *(const f16x8*)&w1T[(size_t)((2 * w + ti) * 16 + lc) * 136 + ks * 32 + lg * 8];
#pragma unroll
    for (int ks = 0; ks < 4; ++ks)
        bw2[ks] = *(const f16x8*)&w2T[(size_t)(w * 16 + lc) * 136 + ks * 32 + lg * 8];
    float bias10 = b1[32 * w + 2 * lc], bias11 = b1[32 * w + 2 * lc + 1];
    float bias2 = b2[w * 16 + lc];

    for (int tile = blockIdx.x; tile < NT_N; tile += gridDim.x) {
        int n0 = tile * 32;
        {
            int nl = tid >> 3, part = tid & 7;
            int n = n0 + nl;
            *(f16x8*)&cin[nl][part * 8] = *(const f16x8*)&h16[(size_t)n * 64 + part * 8];
            if (CSR) {
                float a[8] = {0.f, 0.f, 0.f, 0.f, 0.f, 0.f, 0.f, 0.f};
                int s = rowptr[n], e = rowptr[n + 1];
                for (int jj = s; jj < e; ++jj) {
                    f16x8 m = *(const f16x8*)&emsgS[(size_t)jj * 64 + part * 8];
#pragma unroll
                    for (int q = 0; q < 8; ++q) a[q] += (float)m[q];
                }
                f16x8 o;
#pragma unroll
                for (int q = 0; q < 8; ++q) o[q] = (_Float16)a[q];
                *(f16x8*)&cin[nl][64 + part * 8] = o;
            } else {
                f32x4 xx = *(const f32x4*)&agg[(size_t)n * 64 + part * 8];
                f32x4 yy = *(const f32x4*)&agg[(size_t)n * 64 + part * 8 + 4];
                f16x8 o;
                o[0] = (_Float16)xx[0]; o[1] = (_Float16)xx[1]; o[2] = (_Float16)xx[2]; o[3] = (_Float16)xx[3];
                o[4] = (_Float16)yy[0]; o[5] = (_Float16)yy[1]; o[6] = (_Float16)yy[2]; o[7] = (_Float16)yy[3];
                *(f16x8*)&cin[nl][64 + part * 8] = o;
            }
        }
        __syncthreads();
        f32x4 acc[2][2];
        acc[0][0] = acc[0][1] = acc[1][0] = acc[1][1] = (f32x4){0.f, 0.f, 0.f, 0.f};
#pragma unroll
        for (int ks = 0; ks < 4; ++ks) {
            f16x8 a0 = *(const f16x8*)&cin[lc][ks * 32 + lg * 8];
            f16x8 a1 = *(const f16x8*)&cin[16 + lc][ks * 32 + lg * 8];
#pragma unroll
            for (int ti = 0; ti < 2; ++ti) {
                acc[0][ti] = MFMA16(a0, bw1[ti][ks], acc[0][ti]);
                acc[1][ti] = MFMA16(a1, bw1[ti][ks], acc[1][ti]);
            }
        }
#pragma unroll
        for (int rt = 0; rt < 2; ++rt)
#pragma unroll
            for (int j = 0; j < 4; ++j) {
                f16x2 p;
                p[0] = (_Float16)fsilu_(acc[rt][0][j] + bias10);
                p[1] = (_Float16)fsilu_(acc[rt][1][j] + bias11);
                *(f16x2*)&h1[rt * 16 + lg * 4 + j][32 * w + 2 * lc] = p;
            }
        __syncthreads();
        f32x4 c2[2];
        c2[0] = c2[1] = (f32x4){0.f, 0.f, 0.f, 0.f};
#pragma unroll
        for (int ks = 0; ks < 4; ++ks) {
            f16x8 a0 = *(const f16x8*)&h1[lc][ks * 32 + lg * 8];
            f16x8 a1 = *(const f16x8*)&h1[16 + lc][ks * 32 + lg * 8];
            c2[0] = MFMA16(a0, bw2[ks], c2[0]);
            c2[1] = MFMA16(a1, bw2[ks], c2[1]);
        }
#pragma unroll
        for (int rt = 0; rt < 2; ++rt)
#pragma unroll
            for (int j = 0; j < 4; ++j) {
                int rl = rt * 16 + lg * 4 + j, colc = w * 16 + lc;
                vbuf[rl][colc] = h32[(size_t)(n0 + rl) * 64 + colc] + c2[rt][j] + bias2;
            }
        __syncthreads();
        {
            int r = w * 8 + (lane >> 3), sub = lane & 7;
            f32x4 v0 = *(const f32x4*)&vbuf[r][sub * 8];
            f32x4 v1 = *(const f32x4*)&vbuf[r][sub * 8 + 4];
            float s = v0[0] + v0[1] + v0[2] + v0[3] + v1[0] + v1[1] + v1[2] + v1[3];
            float sq = v0[0]*v0[0] + v0[1]*v0[1] + v0[2]*v0[2] + v0[3]*v0[3]
                     + v1[0]*v1[0] + v1[1]*v1[1] + v1[2]*v1[2] + v1[3]*v1[3];
            s += __shfl_xor(s, 1); s += __shfl_xor(s, 2); s += __shfl_xor(s, 4);
            sq += __shfl_xor(sq, 1); sq += __shfl_xor(sq, 2); sq += __shfl_xor(sq, 4);
            float mu = s * (1.0f / 64.0f);
            float var = sq * (1.0f / 64.0f) - mu * mu;
            float rs = __builtin_amdgcn_rcpf(__builtin_amdgcn_sqrtf(var + 1e-5f));
            size_t base = (size_t)(n0 + r) * 64 + sub * 8;
            f32x4 o0, o1; f16x8 oh;
#pragma unroll
            for (int i = 0; i < 4; ++i) {
                o0[i] = (v0[i] - mu) * rs;
                o1[i] = (v1[i] - mu) * rs;
                oh[i] = (_Float16)o0[i];
                oh[4 + i] = (_Float16)o1[i];
            }
            *(f32x4*)&h32[base] = o0;
            *(f32x4*)&h32[base + 4] = o1;
            *(f16x8*)&h16[base] = oh;
        }
    }
}

__global__ void k_pool_seg(const float* __restrict__ h, const int* __restrict__ batch,
                           float* __restrict__ pooled, float* __restrict__ cnt) {
    int lane = threadIdx.x & 63;
    int wid = blockIdx.x * (blockDim.x >> 6) + (threadIdx.x >> 6);
    int nwav = gridDim.x * (blockDim.x >> 6);
    int chunk = (NN + nwav - 1) / nwav;
    int s = wid * chunk;
    if (s >= NN) return;
    int e = s + chunk; if (e > NN) e = NN;
    int g = batch[s];
    float acc = 0.0f, c = 0.0f;
    for (int n = s; n < e; ++n) {
        int b = batch[n];
        if (b != g) {
            atomicAdd(&pooled[g * 64 + lane], acc);
            if (lane == 0) atomicAdd(&cnt[g], c);
            acc = 0.0f; c = 0.0f; g = b;
        }
        acc += h[(size_t)n * 64 + lane];
        c += 1.0f;
    }
    atomicAdd(&pooled[g * 64 + lane], acc);
    if (lane == 0) atomicAdd(&cnt[g], c);
}

__global__ void k_final(const float* __restrict__ pooled, const float* __restrict__ cnt,
                        const float* __restrict__ ow, const float* __restrict__ ob,
                        float* __restrict__ out) {
    __shared__ float red[2];
    int g = blockIdx.x, o = threadIdx.x;
    float c = fmaxf(cnt[g], 1.0f);
    float acc = ob[o];
#pragma unroll
    for (int j = 0; j < 64; ++j) {
        float pm = fmaxf(pooled[g * 64 + j] / c, 0.0f);
        acc = fmaf(pm, ow[j * 128 + o], acc);
    }
    float ss = acc * acc;
#pragma unroll
    for (int off = 32; off > 0; off >>= 1) ss += __shfl_xor(ss, off);
    if ((o & 63) == 0) red[o >> 6] = ss;
    __syncthreads();
    float nrm = sqrtf(red[0] + red[1]);
    out[g * 128 + o] = acc / fmaxf(nrm, 1e-12f);
}

extern "C" void kernel_launch(void* const* d_in, const int* in_sizes, int n_in,
                              void* d_out, int out_size, void* d_ws, size_t ws_size,
                              hipStream_t stream) {
    const float* x         = (const float*)d_in[0];
    const float* coords_in = (const float*)d_in[1];
    const float* in_w      = (const float*)d_in[2];
    const float* in_b      = (const float*)d_in[3];
    const float* coord_w1  = (const float*)d_in[4];
    const float* coord_b1  = (const float*)d_in[5];
    const float* coord_w2  = (const float*)d_in[6];
    const float* coord_b2  = (const float*)d_in[7];
    const float* ew_w      = (const float*)d_in[8];
    const float* ew_b      = (const float*)d_in[9];
    const float* cn_scale  = (const float*)d_in[10];
    const float* edge_w1   = (const float*)d_in[11];
    const float* edge_b1   = (const float*)d_in[12];
    const float* edge_w2   = (const float*)d_in[13];
    const float* edge_b2   = (const float*)d_in[14];
    const float* node_w1   = (const float*)d_in[15];
    const float* node_b1   = (const float*)d_in[16];
    const float* node_w2   = (const float*)d_in[17];
    const float* node_b2   = (const float*)d_in[18];
    const float* out_w     = (const float*)d_in[19];
    const float* out_b     = (const float*)d_in[20];
    const int* ei          = (const int*)d_in[21];
    const int* batch       = (const int*)d_in[22];
    const int* row = ei;
    const int* col = ei + NE;

    char* wp = (char*)d_ws;
    float* h32    = (float*)wp; wp += (size_t)NN * 64 * 4;
    float* cA     = (float*)wp; wp += (size_t)NN * 3 * 4;
    float* cB     = (float*)wp; wp += (size_t)NN * 3 * 4;
    float* pooled = (float*)wp; wp += (size_t)NG * 64 * 4;
    float* cnt    = (float*)wp; wp += (size_t)NG * 4;
    _Float16* h16  = (_Float16*)wp; wp += (size_t)NN * 64 * 2;
    _Float16* cw1T = (_Float16*)wp; wp += (size_t)NL * SEG0 * 2;
    _Float16* ew1T = (_Float16*)wp; wp += (size_t)NL * SEG1 * 2;
    _Float16* ew2T = (_Float16*)wp; wp += (size_t)NL * SEG2 * 2;
    _Float16* nw1T = (_Float16*)wp; wp += (size_t)NL * SEG3 * 2;
    _Float16* nw2T = (_Float16*)wp; wp += (size_t)NL * SEG4 * 2;
    _Float16* cw2T = (_Float16*)wp; wp += (size_t)NL * SEG5 * 2;
    // CSR region
    int* deg       = (int*)wp;            wp += (size_t)NN * 4;
    int* rowptr    = (int*)wp;            wp += (size_t)(NN + 4) * 4;
    int* pos       = (int*)wp;            wp += (size_t)NN * 4;
    int* bsum      = (int*)wp;            wp += (size_t)SCB * 4;
    int* rowP      = (int*)wp;            wp += (size_t)NE * 4;
    int* colP      = (int*)wp;            wp += (size_t)NE * 4;
    float4* deltas = (float4*)wp;         wp += (size_t)NE * 16;
    _Float16* emsgS= (_Float16*)wp;       wp += (size_t)NE * 64 * 2;
    size_t csr_need = (size_t)(wp - (char*)d_ws);
    float* agg = (float*)deg;  // legacy path union
    bool use_csr = (ws_size >= csr_need);

    if (use_csr) {
        hipMemsetAsync(deg, 0, (size_t)NN * 4, stream);
        k_hist<<<(NE + 255) / 256, 256, 0, stream>>>(row, deg);
        k_scan_part<<<SCB, SCT, 0, stream>>>(deg, bsum);
        k_scan_mid<<<1, SCB, 0, stream>>>(bsum);
        k_scan_fin<<<SCB, SCT, 0, stream>>>(deg, bsum, rowptr);
        hipMemcpyAsync(pos, rowptr, (size_t)NN * 4, hipMemcpyDeviceToDevice, stream);
        k_scatter2<<<(NE + 255) / 256, 256, 0, stream>>>(row, col, pos, rowP, colP);
    }
    k_prep_all<<<(NL * SEGTOT + 255) / 256, 256, 0, stream>>>(
        coord_w1, edge_w1, edge_w2, node_w1, node_w2, coord_w2,
        cw1T, ew1T, ew2T, nw1T, nw2T, cw2T);
    k_init_h<<<(NN * 64 + 255) / 256, 256, 0, stream>>>(x, in_w, in_b, h32, h16);

    const float* cur = coords_in;
    float* nxt = cA;
    for (int l = 0; l < NL; ++l) {
        if (use_csr) {
            k_coord3<1><<<2048, 256, 0, stream>>>(h16, cur, nullptr, rowP, colP, deltas,
                cw1T + (size_t)l * SEG0, coord_b1 + l * 128,
                cw2T + (size_t)l * SEG5, coord_b2 + l * 3,
                ew_w + l * 3, ew_b + l, cn_scale + l);
            k_coord_apply<<<(NN + 255) / 256, 256, 0, stream>>>(cur, nxt, rowptr, deltas);
            k_edge3<1><<<2048, 256, 0, stream>>>(h16, nxt, nullptr, emsgS, rowP, colP,
                ew1T + (size_t)l * SEG1, edge_b1 + l * 128,
                ew2T + (size_t)l * SEG2, edge_b2 + l * 64);
            k_node3<1><<<1024, 256, 0, stream>>>(h32, h16, nullptr, emsgS, rowptr,
                nw1T + (size_t)l * SEG3, node_b1 + l * 128,
                nw2T + (size_t)l * SEG4, node_b2 + l * 64);
        } else {
            hipMemcpyAsync(nxt, cur, (size_t)NN * 3 * sizeof(float), hipMemcpyDeviceToDevice, stream);
            k_coord3<0><<<2048, 256, 0, stream>>>(h16, cur, nxt, row, col, nullptr,
                cw1T + (size_t)l * SEG0, coord_b1 + l * 128,
                cw2T + (size_t)l * SEG5, coord_b2 + l * 3,
                ew_w + l * 3, ew_b + l, cn_scale + l);
            hipMemsetAsync(agg, 0, (size_t)NN * 64 * 4, stream);
            k_edge3<0><<<2048, 256, 0, stream>>>(h16, nxt, agg, nullptr, row, col,
                ew1T + (size_t)l * SEG1, edge_b1 + l * 128,
                ew2T + (size_t)l * SEG2, edge_b2 + l * 64);
            k_node3<0><<<1024, 256, 0, stream>>>(h32, h16, agg, nullptr, nullptr,
                nw1T + (size_t)l * SEG3, node_b1 + l * 128,
                nw2T + (size_t)l * SEG4, node_b2 + l * 64);
        }
        cur = nxt;
        nxt = (nxt == cA) ? cB : cA;
    }
    hipMemsetAsync(pooled, 0, (size_t)(NG * 64 + NG) * sizeof(float), stream);
    k_pool_seg<<<512, 256, 0, stream>>>(h32, batch, pooled, cnt);
    k_final<<<NG, 128, 0, stream>>>(pooled, cnt, out_w, out_b, (float*)d_out);
}